// Round 1
// baseline (1155.981 us; speedup 1.0000x reference)
//
#include <hip/hip_runtime.h>
#include <hip/hip_bf16.h>
#include <math.h>

#define Bq  2
#define Sq  2048
#define Hq  128
#define NHq 8

// ===================== Kernel 1: fused per-head QKV projection =====================
// grid (4096/16, NH), block 128. Each block: 16 x-rows staged in LDS (broadcast reads),
// each thread owns output column e for all 3 matrices of one head.
__global__ __launch_bounds__(128) void qkv_kernel(
    const float* __restrict__ x,
    const float* __restrict__ Wq, const float* __restrict__ bq,
    const float* __restrict__ Wk, const float* __restrict__ bk,
    const float* __restrict__ Wv, const float* __restrict__ bv,
    float* __restrict__ Q, float* __restrict__ K, float* __restrict__ V)
{
    __shared__ float xs[16][128];
    const int e    = threadIdx.x;
    const int h    = blockIdx.y;
    const int row0 = blockIdx.x << 4;

    #pragma unroll
    for (int r = 0; r < 16; ++r)
        xs[r][e] = x[(row0 + r) * Hq + e];
    __syncthreads();

    float aq[16], ak[16], av[16];
    {
        const float bqv = bq[h * Hq + e];
        const float bkv = bk[h * Hq + e];
        const float bvv = bv[h * Hq + e];
        #pragma unroll
        for (int r = 0; r < 16; ++r) { aq[r] = bqv; ak[r] = bkv; av[r] = bvv; }
    }

    const float* wq = Wq + h * Hq * Hq + e;
    const float* wk = Wk + h * Hq * Hq + e;
    const float* wv = Wv + h * Hq * Hq + e;

    for (int d = 0; d < Hq; d += 4) {
        const float q0 = wq[(d + 0) * Hq], q1 = wq[(d + 1) * Hq],
                    q2 = wq[(d + 2) * Hq], q3 = wq[(d + 3) * Hq];
        const float k0 = wk[(d + 0) * Hq], k1 = wk[(d + 1) * Hq],
                    k2 = wk[(d + 2) * Hq], k3 = wk[(d + 3) * Hq];
        const float v0 = wv[(d + 0) * Hq], v1 = wv[(d + 1) * Hq],
                    v2 = wv[(d + 2) * Hq], v3 = wv[(d + 3) * Hq];
        #pragma unroll
        for (int r = 0; r < 16; ++r) {
            const float4 xv = *(const float4*)&xs[r][d];
            aq[r] += xv.x * q0; aq[r] += xv.y * q1; aq[r] += xv.z * q2; aq[r] += xv.w * q3;
            ak[r] += xv.x * k0; ak[r] += xv.y * k1; ak[r] += xv.z * k2; ak[r] += xv.w * k3;
            av[r] += xv.x * v0; av[r] += xv.y * v1; av[r] += xv.z * v2; av[r] += xv.w * v3;
        }
    }

    #pragma unroll
    for (int r = 0; r < 16; ++r) {
        const int row = row0 + r;
        const int b   = row >> 11;          // row / 2048
        const int s   = row & (Sq - 1);
        const int idx = ((b * NHq + h) * Sq + s) * Hq + e;
        Q[idx] = aq[r]; K[idx] = ak[r]; V[idx] = av[r];
    }
}

// ===================== Kernel 2: flash attention (fp32, online softmax) =====================
// grid (S/32, B*NH), block 256. Q-tile 32x128 (scaled by 1/sqrt(H) on load).
// Score phase: thread -> rows {t>>4, (t>>4)+16}, cols {t&15, (t&15)+16} (2x2 micro-tile).
// PV phase: thread -> row t>>3, cols (t&7)*16 .. +15.
#define QT 32
#define KT 32
#define LSTR 132   // padded LDS stride (floats): spreads rows across banks, keeps 16B align
#define PSTR 36

__global__ __launch_bounds__(256) void attn_kernel(
    const float* __restrict__ Q, const float* __restrict__ K,
    const float* __restrict__ V, float* __restrict__ O)
{
    __shared__ float Qs[QT][LSTR];
    __shared__ float Ks[KT][LSTR];
    __shared__ float Vs[KT][LSTR];
    __shared__ float Ps[QT][PSTR];
    __shared__ float mbuf[QT], lbuf[QT], sbuf[QT];

    const int t  = threadIdx.x;
    const int bh = blockIdx.y;
    const int q0 = blockIdx.x * QT;

    const float* Qb = Q + (size_t)bh * Sq * Hq;
    const float* Kb = K + (size_t)bh * Sq * Hq;
    const float* Vb = V + (size_t)bh * Sq * Hq;

    for (int idx = t; idx < QT * Hq; idx += 256) {
        const int r = idx >> 7, e2 = idx & 127;
        Qs[r][e2] = Qb[(q0 + r) * Hq + e2] * 0.08838834764831845f; // 1/sqrt(128)
    }
    if (t < QT) { mbuf[t] = -1e30f; lbuf[t] = 0.0f; }

    const int r0 = t >> 4;         // 0..15
    const int r1 = r0 + 16;
    const int c0 = t & 15;
    const int c1 = c0 + 16;

    const int pr = t >> 3;         // 0..31
    const int pe = (t & 7) << 4;   // 0,16,...,112

    float4 o0 = {0,0,0,0}, o1 = {0,0,0,0}, o2 = {0,0,0,0}, o3 = {0,0,0,0};

    __syncthreads();

    for (int k0 = 0; k0 < Sq; k0 += KT) {
        for (int idx = t; idx < KT * Hq; idx += 256) {
            const int r = idx >> 7, e2 = idx & 127;
            Ks[r][e2] = Kb[(k0 + r) * Hq + e2];
            Vs[r][e2] = Vb[(k0 + r) * Hq + e2];
        }
        __syncthreads();

        // ---- scores: 2x2 per thread over e=0..127 ----
        float s00 = 0.f, s01 = 0.f, s10 = 0.f, s11 = 0.f;
        for (int e2 = 0; e2 < Hq; e2 += 4) {
            const float4 qa = *(const float4*)&Qs[r0][e2];
            const float4 qb = *(const float4*)&Qs[r1][e2];
            const float4 ka = *(const float4*)&Ks[c0][e2];
            const float4 kb = *(const float4*)&Ks[c1][e2];
            s00 += qa.x*ka.x + qa.y*ka.y + qa.z*ka.z + qa.w*ka.w;
            s01 += qa.x*kb.x + qa.y*kb.y + qa.z*kb.z + qa.w*kb.w;
            s10 += qb.x*ka.x + qb.y*ka.y + qb.z*ka.z + qb.w*ka.w;
            s11 += qb.x*kb.x + qb.y*kb.y + qb.z*kb.z + qb.w*kb.w;
        }

        // ---- online softmax: per-row reduce across the 16-lane group ----
        float mx0 = fmaxf(s00, s01);
        float mx1 = fmaxf(s10, s11);
        #pragma unroll
        for (int mm = 1; mm <= 8; mm <<= 1) {
            mx0 = fmaxf(mx0, __shfl_xor(mx0, mm));
            mx1 = fmaxf(mx1, __shfl_xor(mx1, mm));
        }
        const float mp0 = mbuf[r0], mp1 = mbuf[r1];
        const float mn0 = fmaxf(mp0, mx0), mn1 = fmaxf(mp1, mx1);
        const float p00 = __expf(s00 - mn0), p01 = __expf(s01 - mn0);
        const float p10 = __expf(s10 - mn1), p11 = __expf(s11 - mn1);
        float rs0 = p00 + p01, rs1 = p10 + p11;
        #pragma unroll
        for (int mm = 1; mm <= 8; mm <<= 1) {
            rs0 += __shfl_xor(rs0, mm);
            rs1 += __shfl_xor(rs1, mm);
        }
        Ps[r0][c0] = p00; Ps[r0][c1] = p01;
        Ps[r1][c0] = p10; Ps[r1][c1] = p11;
        if ((t & 15) == 0) {
            const float sc0 = __expf(mp0 - mn0);  // first iter: exp(-1e30-x) = 0
            const float sc1 = __expf(mp1 - mn1);
            mbuf[r0] = mn0; mbuf[r1] = mn1;
            lbuf[r0] = lbuf[r0] * sc0 + rs0;
            lbuf[r1] = lbuf[r1] * sc1 + rs1;
            sbuf[r0] = sc0; sbuf[r1] = sc1;
        }
        __syncthreads();

        // ---- PV accumulate ----
        const float sc = sbuf[pr];
        o0.x *= sc; o0.y *= sc; o0.z *= sc; o0.w *= sc;
        o1.x *= sc; o1.y *= sc; o1.z *= sc; o1.w *= sc;
        o2.x *= sc; o2.y *= sc; o2.z *= sc; o2.w *= sc;
        o3.x *= sc; o3.y *= sc; o3.z *= sc; o3.w *= sc;
        for (int j = 0; j < KT; ++j) {
            const float p  = Ps[pr][j];
            const float4 v0 = *(const float4*)&Vs[j][pe];
            const float4 v1 = *(const float4*)&Vs[j][pe + 4];
            const float4 v2 = *(const float4*)&Vs[j][pe + 8];
            const float4 v3 = *(const float4*)&Vs[j][pe + 12];
            o0.x += p * v0.x; o0.y += p * v0.y; o0.z += p * v0.z; o0.w += p * v0.w;
            o1.x += p * v1.x; o1.y += p * v1.y; o1.z += p * v1.z; o1.w += p * v1.w;
            o2.x += p * v2.x; o2.y += p * v2.y; o2.z += p * v2.z; o2.w += p * v2.w;
            o3.x += p * v3.x; o3.y += p * v3.y; o3.z += p * v3.z; o3.w += p * v3.w;
        }
        __syncthreads();
    }

    const float inv = 1.0f / lbuf[pr];
    const int b = bh >> 3, h = bh & 7;
    float* op = O + (size_t)(b * Sq + q0 + pr) * (NHq * Hq) + h * Hq + pe;
    o0.x *= inv; o0.y *= inv; o0.z *= inv; o0.w *= inv;
    o1.x *= inv; o1.y *= inv; o1.z *= inv; o1.w *= inv;
    o2.x *= inv; o2.y *= inv; o2.z *= inv; o2.w *= inv;
    o3.x *= inv; o3.y *= inv; o3.z *= inv; o3.w *= inv;
    *(float4*)&op[0]  = o0;
    *(float4*)&op[4]  = o1;
    *(float4*)&op[8]  = o2;
    *(float4*)&op[12] = o3;
}

// ===================== Kernel 3: Wo projection [4096,1024]@[1024,128]+bo =====================
__global__ __launch_bounds__(128) void wo_kernel(
    const float* __restrict__ o, const float* __restrict__ Wo,
    const float* __restrict__ bo, float* __restrict__ y0)
{
    __shared__ float os[16][128];
    const int e = threadIdx.x;
    const int row0 = blockIdx.x << 4;
    float acc[16];
    const float bv = bo[e];
    #pragma unroll
    for (int r = 0; r < 16; ++r) acc[r] = bv;

    for (int dc = 0; dc < NHq * Hq; dc += 128) {
        __syncthreads();
        #pragma unroll
        for (int r = 0; r < 16; ++r)
            os[r][e] = o[(size_t)(row0 + r) * (NHq * Hq) + dc + e];
        __syncthreads();
        const float* wp = Wo + (size_t)dc * Hq + e;
        for (int d = 0; d < 128; d += 4) {
            const float w0 = wp[(d+0)*Hq], w1 = wp[(d+1)*Hq],
                        w2 = wp[(d+2)*Hq], w3 = wp[(d+3)*Hq];
            #pragma unroll
            for (int r = 0; r < 16; ++r) {
                const float4 xv = *(const float4*)&os[r][d];
                acc[r] += xv.x*w0 + xv.y*w1 + xv.z*w2 + xv.w*w3;
            }
        }
    }
    #pragma unroll
    for (int r = 0; r < 16; ++r)
        y0[(row0 + r) * Hq + e] = acc[r];
}

// ===================== Kernel 4a: h1 = relu(y@W1 + b1) [4096,128]@[128,256] =====================
__global__ __launch_bounds__(256) void ffn1_kernel(
    const float* __restrict__ y, const float* __restrict__ W1,
    const float* __restrict__ b1, float* __restrict__ h1)
{
    __shared__ float ys[16][128];
    const int e = threadIdx.x;          // 0..255
    const int row0 = blockIdx.x << 4;
    for (int idx = e; idx < 16 * 128; idx += 256)
        ys[idx >> 7][idx & 127] = y[(row0 << 7) + idx];
    __syncthreads();
    float acc[16];
    const float bv = b1[e];
    #pragma unroll
    for (int r = 0; r < 16; ++r) acc[r] = bv;
    const float* wp = W1 + e;
    for (int d = 0; d < 128; d += 4) {
        const float w0 = wp[(d+0)*256], w1 = wp[(d+1)*256],
                    w2 = wp[(d+2)*256], w3 = wp[(d+3)*256];
        #pragma unroll
        for (int r = 0; r < 16; ++r) {
            const float4 xv = *(const float4*)&ys[r][d];
            acc[r] += xv.x*w0 + xv.y*w1 + xv.z*w2 + xv.w*w3;
        }
    }
    #pragma unroll
    for (int r = 0; r < 16; ++r)
        h1[(size_t)(row0 + r) * 256 + e] = fmaxf(acc[r], 0.0f);
}

// ===================== Kernel 4b: f = relu(h1@W2 + b2) [4096,256]@[256,128] =====================
__global__ __launch_bounds__(128) void ffn2_kernel(
    const float* __restrict__ h1, const float* __restrict__ W2,
    const float* __restrict__ b2, float* __restrict__ f)
{
    __shared__ float hs[16][256];
    const int e = threadIdx.x;
    const int row0 = blockIdx.x << 4;
    for (int idx = e; idx < 16 * 256; idx += 128)
        hs[idx >> 8][idx & 255] = h1[(size_t)(row0 << 8) + idx];
    __syncthreads();
    float acc[16];
    const float bv = b2[e];
    #pragma unroll
    for (int r = 0; r < 16; ++r) acc[r] = bv;
    const float* wp = W2 + e;
    for (int d = 0; d < 256; d += 4) {
        const float w0 = wp[(d+0)*Hq], w1 = wp[(d+1)*Hq],
                    w2 = wp[(d+2)*Hq], w3 = wp[(d+3)*Hq];
        #pragma unroll
        for (int r = 0; r < 16; ++r) {
            const float4 xv = *(const float4*)&hs[r][d];
            acc[r] += xv.x*w0 + xv.y*w1 + xv.z*w2 + xv.w*w3;
        }
    }
    #pragma unroll
    for (int r = 0; r < 16; ++r)
        f[(row0 + r) * Hq + e] = fmaxf(acc[r], 0.0f);
}

// ===================== LayerNorm (optional residual), 1 wave per 128-wide row =====================
__global__ __launch_bounds__(256) void ln_kernel(
    const float* __restrict__ in, const float* __restrict__ res,
    const float* __restrict__ g, const float* __restrict__ bta,
    float* __restrict__ out)
{
    const int lane = threadIdx.x & 63;
    const int row  = (blockIdx.x << 2) + (threadIdx.x >> 6);
    const int base = row * 128 + lane * 2;
    float2 v = *(const float2*)&in[base];
    if (res) {
        const float2 rv = *(const float2*)&res[base];
        v.x += rv.x; v.y += rv.y;
    }
    float s  = v.x + v.y;
    float sq = v.x * v.x + v.y * v.y;
    #pragma unroll
    for (int mm = 1; mm <= 32; mm <<= 1) {
        s  += __shfl_xor(s, mm);
        sq += __shfl_xor(sq, mm);
    }
    const float mean = s * (1.0f / 128.0f);
    const float var  = sq * (1.0f / 128.0f) - mean * mean;
    const float rstd = rsqrtf(var + 1e-5f);
    const float2 gv = *(const float2*)&g[lane * 2];
    const float2 bv = *(const float2*)&bta[lane * 2];
    float2 o;
    o.x = (v.x - mean) * rstd * gv.x + bv.x;
    o.y = (v.y - mean) * rstd * gv.y + bv.y;
    *(float2*)&out[base] = o;
}

extern "C" void kernel_launch(void* const* d_in, const int* in_sizes, int n_in,
                              void* d_out, int out_size, void* d_ws, size_t ws_size,
                              hipStream_t stream)
{
    const float* x   = (const float*)d_in[0];
    const float* Wq  = (const float*)d_in[1];
    const float* bq  = (const float*)d_in[2];
    const float* Wk  = (const float*)d_in[3];
    const float* bk  = (const float*)d_in[4];
    const float* Wv  = (const float*)d_in[5];
    const float* bv  = (const float*)d_in[6];
    const float* Wo  = (const float*)d_in[7];
    const float* bo  = (const float*)d_in[8];
    const float* W1  = (const float*)d_in[9];
    const float* b1  = (const float*)d_in[10];
    const float* W2  = (const float*)d_in[11];
    const float* b2  = (const float*)d_in[12];
    const float* g1  = (const float*)d_in[13];
    const float* be1 = (const float*)d_in[14];
    const float* g2  = (const float*)d_in[15];
    const float* be2 = (const float*)d_in[16];
    (void)in_sizes; (void)n_in; (void)out_size; (void)ws_size;

    float* ws = (float*)d_ws;
    const size_t QKV = (size_t)Bq * NHq * Sq * Hq;    // 4,194,304 floats
    float* Q = ws;
    float* K = Q + QKV;
    float* V = K + QKV;
    float* o = V + QKV;                               // 4096 x 1024
    // Q/K/V are dead after attention: alias the small tail buffers into Q's region.
    float* y0 = Q;                                    // 4096 x 128
    float* y  = Q + 1048576;                          // 4096 x 128
    float* h1 = Q + 2097152;                          // 4096 x 256
    float* f  = Q + 3145728;                          // 4096 x 128

    qkv_kernel <<<dim3(256, NHq),        128, 0, stream>>>(x, Wq, bq, Wk, bk, Wv, bv, Q, K, V);
    attn_kernel<<<dim3(Sq / 32, Bq*NHq), 256, 0, stream>>>(Q, K, V, o);
    wo_kernel  <<<256,                   128, 0, stream>>>(o, Wo, bo, y0);
    ln_kernel  <<<1024,                  256, 0, stream>>>(y0, nullptr, g1, be1, y);
    ffn1_kernel<<<256,                   256, 0, stream>>>(y, W1, b1, h1);
    ffn2_kernel<<<256,                   128, 0, stream>>>(h1, W2, b2, f);
    ln_kernel  <<<1024,                  256, 0, stream>>>(y, f, g2, be2, (float*)d_out);
}

// Round 2
// 322.404 us; speedup vs baseline: 3.5855x; 3.5855x over previous
//
#include <hip/hip_runtime.h>
#include <math.h>

#define Bq  2
#define Sq  2048
#define Hq  128
#define NHq 8

typedef __attribute__((ext_vector_type(8))) short bf16x8;
typedef __attribute__((ext_vector_type(4))) float f32x4;
typedef unsigned short ushort_t;
typedef unsigned int uint_t;

__device__ inline ushort_t f2bf(float f) {
    union { float f; uint_t u; } c; c.f = f;
    uint_t u = c.u + 0x7FFFu + ((c.u >> 16) & 1u);   // RNE
    return (ushort_t)(u >> 16);
}

// ===================== Kernel 1: fused per-head QKV projection (bf16 out) =====================
// grid (4096/16, NH), block 128. Q pre-scaled by 1/sqrt(128).
__global__ __launch_bounds__(128) void qkv_kernel(
    const float* __restrict__ x,
    const float* __restrict__ Wq, const float* __restrict__ bq,
    const float* __restrict__ Wk, const float* __restrict__ bk,
    const float* __restrict__ Wv, const float* __restrict__ bv,
    ushort_t* __restrict__ Q, ushort_t* __restrict__ K, ushort_t* __restrict__ V)
{
    __shared__ float xs[16][128];
    const int e    = threadIdx.x;
    const int h    = blockIdx.y;
    const int row0 = blockIdx.x << 4;

    #pragma unroll
    for (int r = 0; r < 16; ++r)
        xs[r][e] = x[(row0 + r) * Hq + e];
    __syncthreads();

    float aq[16], ak[16], av[16];
    {
        const float bqv = bq[h * Hq + e];
        const float bkv = bk[h * Hq + e];
        const float bvv = bv[h * Hq + e];
        #pragma unroll
        for (int r = 0; r < 16; ++r) { aq[r] = bqv; ak[r] = bkv; av[r] = bvv; }
    }

    const float* wq = Wq + h * Hq * Hq + e;
    const float* wk = Wk + h * Hq * Hq + e;
    const float* wv = Wv + h * Hq * Hq + e;

    for (int d = 0; d < Hq; d += 4) {
        const float q0 = wq[(d + 0) * Hq], q1 = wq[(d + 1) * Hq],
                    q2 = wq[(d + 2) * Hq], q3 = wq[(d + 3) * Hq];
        const float k0 = wk[(d + 0) * Hq], k1 = wk[(d + 1) * Hq],
                    k2 = wk[(d + 2) * Hq], k3 = wk[(d + 3) * Hq];
        const float v0 = wv[(d + 0) * Hq], v1 = wv[(d + 1) * Hq],
                    v2 = wv[(d + 2) * Hq], v3 = wv[(d + 3) * Hq];
        #pragma unroll
        for (int r = 0; r < 16; ++r) {
            const float4 xv = *(const float4*)&xs[r][d];
            aq[r] += xv.x * q0; aq[r] += xv.y * q1; aq[r] += xv.z * q2; aq[r] += xv.w * q3;
            ak[r] += xv.x * k0; ak[r] += xv.y * k1; ak[r] += xv.z * k2; ak[r] += xv.w * k3;
            av[r] += xv.x * v0; av[r] += xv.y * v1; av[r] += xv.z * v2; av[r] += xv.w * v3;
        }
    }

    #pragma unroll
    for (int r = 0; r < 16; ++r) {
        const int row = row0 + r;
        const int b   = row >> 11;
        const int s   = row & (Sq - 1);
        const int idx = ((b * NHq + h) * Sq + s) * Hq + e;
        Q[idx] = f2bf(aq[r] * 0.08838834764831845f);  // 1/sqrt(128) folded in
        K[idx] = f2bf(ak[r]);
        V[idx] = f2bf(av[r]);
    }
}

// ===================== Kernel 2: flash attention, bf16 MFMA =====================
// grid (S/64, B*NH), block 256 (4 waves). Each wave owns a 16-row Q strip.
// Per KV-tile (64): stage K row-major (stride 136), V transposed (Vt[128][72]).
// QK^T: A=Q-frag (regs), B=K rows from LDS. Softmax in regs (C-layout:
// row=(lane>>4)*4+reg, col=lane&15 [m89]). P -> LDS (bf16) -> A-frag reads.
// PV: B = Vt rows. fp32 accumulators throughout.
#define KSTR 136   // K LDS row stride (elems): 272B -> 2-way bank alias (free)
#define VSTR 72    // Vt/Ps stride: 144B, 16B-aligned, 2-way alias

__global__ __launch_bounds__(256) void attn_kernel(
    const ushort_t* __restrict__ Q, const ushort_t* __restrict__ K,
    const ushort_t* __restrict__ V, float* __restrict__ O)
{
    __shared__ ushort_t Ks[64][KSTR];
    __shared__ ushort_t Vt[128][VSTR];
    __shared__ ushort_t Ps[64][VSTR];

    const int t  = threadIdx.x;
    const int w  = t >> 6;          // wave 0..3
    const int l  = t & 63;
    const int lg = l >> 4;          // 0..3
    const int ln = l & 15;

    const int bh = blockIdx.y;
    const int q0 = blockIdx.x * 64;
    const size_t base = (size_t)bh * Sq * Hq;
    const ushort_t* Qp = Q + base;
    const ushort_t* Kp = K + base;
    const ushort_t* Vp = V + base;

    // Q fragments (A-layout: m=ln, k = kc*32 + lg*8 + j)
    bf16x8 qf[4];
    {
        const int qrow = q0 + w * 16 + ln;
        #pragma unroll
        for (int kc = 0; kc < 4; ++kc)
            qf[kc] = *(const bf16x8*)(Qp + (size_t)qrow * Hq + kc * 32 + lg * 8);
    }

    f32x4 po[8];
    #pragma unroll
    for (int dt = 0; dt < 8; ++dt) po[dt] = (f32x4){0.f, 0.f, 0.f, 0.f};
    float m_[4], l_[4];
    #pragma unroll
    for (int j = 0; j < 4; ++j) { m_[j] = -1e30f; l_[j] = 0.f; }

    for (int k0 = 0; k0 < Sq; k0 += 64) {
        // ---- stage K tile row-major: 1024 16B-groups, coalesced ----
        #pragma unroll
        for (int i = 0; i < 4; ++i) {
            const int task = t + i * 256;
            const int row = task >> 4, c8 = (task & 15) * 8;
            *(bf16x8*)&Ks[row][c8] = *(const bf16x8*)(Kp + (size_t)(k0 + row) * Hq + c8);
        }
        // ---- stage V transposed: lane pair-packs 2 kv rows per dim ----
        #pragma unroll
        for (int i = 0; i < 2; ++i) {
            const int task = t + i * 256;
            const int kv2 = (task & 31) * 2;        // consecutive lanes -> consecutive kv pairs (bank-spread writes)
            const int d8  = (task >> 5) * 8;
            const bf16x8 v0 = *(const bf16x8*)(Vp + (size_t)(k0 + kv2) * Hq + d8);
            const bf16x8 v1 = *(const bf16x8*)(Vp + (size_t)(k0 + kv2 + 1) * Hq + d8);
            #pragma unroll
            for (int jj = 0; jj < 8; ++jj) {
                const uint_t pk = (uint_t)(ushort_t)v0[jj] | ((uint_t)(ushort_t)v1[jj] << 16);
                *(uint_t*)&Vt[d8 + jj][kv2] = pk;
            }
        }
        __syncthreads();

        // ---- QK^T: wave strip (16 q-rows) x 64 kv-cols ----
        f32x4 sa[4];
        #pragma unroll
        for (int ct = 0; ct < 4; ++ct) {
            sa[ct] = (f32x4){0.f, 0.f, 0.f, 0.f};
            #pragma unroll
            for (int kc = 0; kc < 4; ++kc) {
                const bf16x8 bk = *(const bf16x8*)&Ks[ct * 16 + ln][kc * 32 + lg * 8];
                sa[ct] = __builtin_amdgcn_mfma_f32_16x16x32_bf16(qf[kc], bk, sa[ct], 0, 0, 0);
            }
        }

        // ---- online softmax: lane owns rows lg*4+j (j=0..3), col ct*16+ln ----
        float p[4][4], sc[4];
        #pragma unroll
        for (int j = 0; j < 4; ++j) {
            float mx = fmaxf(fmaxf(sa[0][j], sa[1][j]), fmaxf(sa[2][j], sa[3][j]));
            mx = fmaxf(mx, __shfl_xor(mx, 1));
            mx = fmaxf(mx, __shfl_xor(mx, 2));
            mx = fmaxf(mx, __shfl_xor(mx, 4));
            mx = fmaxf(mx, __shfl_xor(mx, 8));
            const float mn = fmaxf(m_[j], mx);
            float r = 0.f;
            #pragma unroll
            for (int ct = 0; ct < 4; ++ct) { p[ct][j] = __expf(sa[ct][j] - mn); r += p[ct][j]; }
            r += __shfl_xor(r, 1); r += __shfl_xor(r, 2);
            r += __shfl_xor(r, 4); r += __shfl_xor(r, 8);
            sc[j] = __expf(m_[j] - mn);   // first tile: exp(-1e30) = 0
            l_[j] = l_[j] * sc[j] + r;
            m_[j] = mn;
        }

        // P -> LDS (wave-private strip; same-wave DS ops are in-order)
        #pragma unroll
        for (int ct = 0; ct < 4; ++ct)
            #pragma unroll
            for (int j = 0; j < 4; ++j)
                Ps[w * 16 + lg * 4 + j][ct * 16 + ln] = f2bf(p[ct][j]);

        // rescale O accumulators
        #pragma unroll
        for (int dt = 0; dt < 8; ++dt)
            #pragma unroll
            for (int j = 0; j < 4; ++j) po[dt][j] *= sc[j];

        // ---- PV: A = P strip, B = Vt rows ----
        bf16x8 pa[2];
        #pragma unroll
        for (int kc = 0; kc < 2; ++kc)
            pa[kc] = *(const bf16x8*)&Ps[w * 16 + ln][kc * 32 + lg * 8];
        #pragma unroll
        for (int dt = 0; dt < 8; ++dt) {
            #pragma unroll
            for (int kc = 0; kc < 2; ++kc) {
                const bf16x8 bv = *(const bf16x8*)&Vt[dt * 16 + ln][kc * 32 + lg * 8];
                po[dt] = __builtin_amdgcn_mfma_f32_16x16x32_bf16(pa[kc], bv, po[dt], 0, 0, 0);
            }
        }
        __syncthreads();
    }

    // epilogue: O[q][h*128+d] = acc / l
    const int b = bh >> 3, h = bh & 7;
    #pragma unroll
    for (int j = 0; j < 4; ++j) {
        const float inv = 1.0f / l_[j];
        const int qrow = q0 + w * 16 + lg * 4 + j;
        float* op = O + (size_t)(b * Sq + qrow) * (NHq * Hq) + h * Hq + ln;
        #pragma unroll
        for (int dt = 0; dt < 8; ++dt)
            op[dt * 16] = po[dt][j] * inv;
    }
}

// ===================== Kernel 3: Wo projection [4096,1024]@[1024,128]+bo =====================
__global__ __launch_bounds__(128) void wo_kernel(
    const float* __restrict__ o, const float* __restrict__ Wo,
    const float* __restrict__ bo, float* __restrict__ y0)
{
    __shared__ float os[16][128];
    const int e = threadIdx.x;
    const int row0 = blockIdx.x << 4;
    float acc[16];
    const float bv = bo[e];
    #pragma unroll
    for (int r = 0; r < 16; ++r) acc[r] = bv;

    for (int dc = 0; dc < NHq * Hq; dc += 128) {
        __syncthreads();
        #pragma unroll
        for (int r = 0; r < 16; ++r)
            os[r][e] = o[(size_t)(row0 + r) * (NHq * Hq) + dc + e];
        __syncthreads();
        const float* wp = Wo + (size_t)dc * Hq + e;
        for (int d = 0; d < 128; d += 4) {
            const float w0 = wp[(d+0)*Hq], w1 = wp[(d+1)*Hq],
                        w2 = wp[(d+2)*Hq], w3 = wp[(d+3)*Hq];
            #pragma unroll
            for (int r = 0; r < 16; ++r) {
                const float4 xv = *(const float4*)&os[r][d];
                acc[r] += xv.x*w0 + xv.y*w1 + xv.z*w2 + xv.w*w3;
            }
        }
    }
    #pragma unroll
    for (int r = 0; r < 16; ++r)
        y0[(row0 + r) * Hq + e] = acc[r];
}

// ===================== Kernel 4a: h1 = relu(y@W1 + b1) =====================
__global__ __launch_bounds__(256) void ffn1_kernel(
    const float* __restrict__ y, const float* __restrict__ W1,
    const float* __restrict__ b1, float* __restrict__ h1)
{
    __shared__ float ys[16][128];
    const int e = threadIdx.x;
    const int row0 = blockIdx.x << 4;
    for (int idx = e; idx < 16 * 128; idx += 256)
        ys[idx >> 7][idx & 127] = y[(row0 << 7) + idx];
    __syncthreads();
    float acc[16];
    const float bv = b1[e];
    #pragma unroll
    for (int r = 0; r < 16; ++r) acc[r] = bv;
    const float* wp = W1 + e;
    for (int d = 0; d < 128; d += 4) {
        const float w0 = wp[(d+0)*256], w1 = wp[(d+1)*256],
                    w2 = wp[(d+2)*256], w3 = wp[(d+3)*256];
        #pragma unroll
        for (int r = 0; r < 16; ++r) {
            const float4 xv = *(const float4*)&ys[r][d];
            acc[r] += xv.x*w0 + xv.y*w1 + xv.z*w2 + xv.w*w3;
        }
    }
    #pragma unroll
    for (int r = 0; r < 16; ++r)
        h1[(size_t)(row0 + r) * 256 + e] = fmaxf(acc[r], 0.0f);
}

// ===================== Kernel 4b: f = relu(h1@W2 + b2) =====================
__global__ __launch_bounds__(128) void ffn2_kernel(
    const float* __restrict__ h1, const float* __restrict__ W2,
    const float* __restrict__ b2, float* __restrict__ f)
{
    __shared__ float hs[16][256];
    const int e = threadIdx.x;
    const int row0 = blockIdx.x << 4;
    for (int idx = e; idx < 16 * 256; idx += 128)
        hs[idx >> 8][idx & 255] = h1[(size_t)(row0 << 8) + idx];
    __syncthreads();
    float acc[16];
    const float bv = b2[e];
    #pragma unroll
    for (int r = 0; r < 16; ++r) acc[r] = bv;
    const float* wp = W2 + e;
    for (int d = 0; d < 256; d += 4) {
        const float w0 = wp[(d+0)*Hq], w1 = wp[(d+1)*Hq],
                    w2 = wp[(d+2)*Hq], w3 = wp[(d+3)*Hq];
        #pragma unroll
        for (int r = 0; r < 16; ++r) {
            const float4 xv = *(const float4*)&hs[r][d];
            acc[r] += xv.x*w0 + xv.y*w1 + xv.z*w2 + xv.w*w3;
        }
    }
    #pragma unroll
    for (int r = 0; r < 16; ++r)
        f[(row0 + r) * Hq + e] = fmaxf(acc[r], 0.0f);
}

// ===================== LayerNorm (optional residual) =====================
__global__ __launch_bounds__(256) void ln_kernel(
    const float* __restrict__ in, const float* __restrict__ res,
    const float* __restrict__ g, const float* __restrict__ bta,
    float* __restrict__ out)
{
    const int lane = threadIdx.x & 63;
    const int row  = (blockIdx.x << 2) + (threadIdx.x >> 6);
    const int base = row * 128 + lane * 2;
    float2 v = *(const float2*)&in[base];
    if (res) {
        const float2 rv = *(const float2*)&res[base];
        v.x += rv.x; v.y += rv.y;
    }
    float s  = v.x + v.y;
    float sq = v.x * v.x + v.y * v.y;
    #pragma unroll
    for (int mm = 1; mm <= 32; mm <<= 1) {
        s  += __shfl_xor(s, mm);
        sq += __shfl_xor(sq, mm);
    }
    const float mean = s * (1.0f / 128.0f);
    const float var  = sq * (1.0f / 128.0f) - mean * mean;
    const float rstd = rsqrtf(var + 1e-5f);
    const float2 gv = *(const float2*)&g[lane * 2];
    const float2 bv = *(const float2*)&bta[lane * 2];
    float2 o;
    o.x = (v.x - mean) * rstd * gv.x + bv.x;
    o.y = (v.y - mean) * rstd * gv.y + bv.y;
    *(float2*)&out[base] = o;
}

extern "C" void kernel_launch(void* const* d_in, const int* in_sizes, int n_in,
                              void* d_out, int out_size, void* d_ws, size_t ws_size,
                              hipStream_t stream)
{
    const float* x   = (const float*)d_in[0];
    const float* Wq  = (const float*)d_in[1];
    const float* bq  = (const float*)d_in[2];
    const float* Wk  = (const float*)d_in[3];
    const float* bk  = (const float*)d_in[4];
    const float* Wv  = (const float*)d_in[5];
    const float* bv  = (const float*)d_in[6];
    const float* Wo  = (const float*)d_in[7];
    const float* bo  = (const float*)d_in[8];
    const float* W1  = (const float*)d_in[9];
    const float* b1  = (const float*)d_in[10];
    const float* W2  = (const float*)d_in[11];
    const float* b2  = (const float*)d_in[12];
    const float* g1  = (const float*)d_in[13];
    const float* be1 = (const float*)d_in[14];
    const float* g2  = (const float*)d_in[15];
    const float* be2 = (const float*)d_in[16];
    (void)in_sizes; (void)n_in; (void)out_size; (void)ws_size;

    const size_t QKV = (size_t)Bq * NHq * Sq * Hq;    // 4,194,304 elems
    ushort_t* Qb = (ushort_t*)d_ws;                   // bf16
    ushort_t* Kb = Qb + QKV;
    ushort_t* Vb = Kb + QKV;
    float* o  = (float*)(Vb + QKV);                   // 4096 x 1024 fp32 (25.2MB offset, 16B-aligned)
    float* y0 = o  + (size_t)4096 * 1024;
    float* y  = y0 + 4096 * 128;
    float* h1 = y  + 4096 * 128;
    float* f  = h1 + 4096 * 256;

    qkv_kernel <<<dim3(256, NHq),        128, 0, stream>>>(x, Wq, bq, Wk, bk, Wv, bv, Qb, Kb, Vb);
    attn_kernel<<<dim3(Sq / 64, Bq*NHq), 256, 0, stream>>>(Qb, Kb, Vb, o);
    wo_kernel  <<<256,                   128, 0, stream>>>(o, Wo, bo, y0);
    ln_kernel  <<<1024,                  256, 0, stream>>>(y0, nullptr, g1, be1, y);
    ffn1_kernel<<<256,                   256, 0, stream>>>(y, W1, b1, h1);
    ffn2_kernel<<<256,                   128, 0, stream>>>(h1, W2, b2, f);
    ln_kernel  <<<1024,                  256, 0, stream>>>(y, f, g2, be2, (float*)d_out);
}

// Round 3
// 149.258 us; speedup vs baseline: 7.7449x; 2.1601x over previous
//
#include <hip/hip_runtime.h>
#include <math.h>

#define Bq  2
#define Sq  2048
#define Hq  128
#define NHq 8

typedef __attribute__((ext_vector_type(8))) short bf16x8;
typedef __attribute__((ext_vector_type(4))) float f32x4;
typedef __attribute__((ext_vector_type(4))) unsigned short ushort4_t;
typedef unsigned short ushort_t;
typedef unsigned int uint_t;

__device__ inline ushort_t f2bf(float f) {
    union { float f; uint_t u; } c; c.f = f;
    uint_t u = c.u + 0x7FFFu + ((c.u >> 16) & 1u);   // RNE
    return (ushort_t)(u >> 16);
}

// async global->LDS, 16B per lane; LDS dest = wave-uniform base + lane*16
#define GLOAD16(gsrc, ldst) \
    __builtin_amdgcn_global_load_lds( \
        (const __attribute__((address_space(1))) unsigned int*)(const void*)(gsrc), \
        (__attribute__((address_space(3))) unsigned int*)(ldst), 16, 0, 0)

// ============ Kernel 0: weight transpose + bf16 convert ============
// grid (128, 27): z<24 -> per-head Wq/Wk/Wv [128,128]; 24:Wo[1024,128]; 25:W1[128,256]; 26:W2[256,128]
// dst[c][r] = bf16(src[r][c])  (Bt layout: [n][k])
__global__ __launch_bounds__(256) void tw_kernel(
    const float* __restrict__ Wq, const float* __restrict__ Wk, const float* __restrict__ Wv,
    const float* __restrict__ Wo, const float* __restrict__ W1, const float* __restrict__ W2,
    ushort_t* __restrict__ Wt_all, ushort_t* __restrict__ Wot,
    ushort_t* __restrict__ W1t, ushort_t* __restrict__ W2t)
{
    const int z = blockIdx.y;
    const float* src; ushort_t* dst; int R, C;
    if (z < 24) { const int h = z & 7;
        src = (z < 8 ? Wq : z < 16 ? Wk : Wv) + h * 16384;
        dst = Wt_all + z * 16384; R = 128; C = 128;
    } else if (z == 24) { src = Wo; dst = Wot; R = 1024; C = 128; }
    else if (z == 25)   { src = W1; dst = W1t; R = 128;  C = 256; }
    else                { src = W2; dst = W2t; R = 256;  C = 128; }

    const int tpc = C >> 5;
    if ((int)blockIdx.x >= (R >> 5) * tpc) return;
    const int r0 = (blockIdx.x / tpc) << 5;
    const int c0 = (blockIdx.x % tpc) << 5;

    __shared__ float ls[32][33];
    const int t = threadIdx.x;
    const int lr = t >> 5, lc = t & 31;
    #pragma unroll
    for (int i = 0; i < 4; ++i)
        ls[lr + i * 8][lc] = src[(size_t)(r0 + lr + i * 8) * C + c0 + lc];
    __syncthreads();
    const int wc = t >> 3, wr0 = (t & 7) << 2;
    ushort4_t o4;
    o4[0] = f2bf(ls[wr0 + 0][wc]); o4[1] = f2bf(ls[wr0 + 1][wc]);
    o4[2] = f2bf(ls[wr0 + 2][wc]); o4[3] = f2bf(ls[wr0 + 3][wc]);
    *(ushort4_t*)&dst[(size_t)(c0 + wc) * R + r0 + wr0] = o4;
}

// ============ Kernel 1: batched QKV projection, MFMA ============
// grid (64, 24), block 256. z: 0-7 Q-head, 8-15 K-head, 16-23 V-head.
// A = x[4096,128] fp32 (converted+swizzled into LDS), Bt = Wt_all[z] [128n][128k].
__global__ __launch_bounds__(256) void qkv_gemm(
    const float* __restrict__ x, const ushort_t* __restrict__ Wt_all,
    const float* __restrict__ bq, const float* __restrict__ bk, const float* __restrict__ bv,
    ushort_t* __restrict__ Qb, ushort_t* __restrict__ Kb, ushort_t* __restrict__ Vb)
{
    __shared__ ushort_t As[64 * 128];
    __shared__ ushort_t Bs[128 * 128];
    const int tid = threadIdx.x;
    const int w = tid >> 6, l = tid & 63, lg = l >> 4, ln = l & 15;
    const int m0 = blockIdx.x << 6;
    const int z  = blockIdx.y;

    // stage A: fp32 -> bf16, XOR-swizzled 16B slots (slot' = slot ^ (row&15))
    #pragma unroll
    for (int i = 0; i < 4; ++i) {
        const int c = tid + i * 256;             // chunk id
        const int row = c >> 4, j = c & 15;
        const float* xp = x + (size_t)(m0 + row) * 128 + j * 8;
        const float4 a = *(const float4*)xp;
        const float4 b = *(const float4*)(xp + 4);
        bf16x8 v;
        v[0]=f2bf(a.x); v[1]=f2bf(a.y); v[2]=f2bf(a.z); v[3]=f2bf(a.w);
        v[4]=f2bf(b.x); v[5]=f2bf(b.y); v[6]=f2bf(b.z); v[7]=f2bf(b.w);
        *(bf16x8*)&As[row * 128 + ((j ^ (row & 15)) << 3)] = v;
    }
    // stage B via global_load_lds, pre-swizzled source
    const ushort_t* Wz = Wt_all + (size_t)z * 16384;
    #pragma unroll
    for (int i = 0; i < 8; ++i) {
        const int seg = w * 8 + i;
        const int row = seg * 4 + (l >> 4);
        const int j = (l & 15) ^ (row & 15);
        GLOAD16(Wz + row * 128 + j * 8, &Bs[seg * 512]);
    }
    __syncthreads();

    bf16x8 af[4];
    #pragma unroll
    for (int kc = 0; kc < 4; ++kc)
        af[kc] = *(const bf16x8*)&As[(w * 16 + ln) * 128 + (((kc * 4 + lg) ^ ln) << 3)];

    f32x4 acc[8];
    #pragma unroll
    for (int nt = 0; nt < 8; ++nt) acc[nt] = (f32x4){0.f,0.f,0.f,0.f};
    #pragma unroll
    for (int nt = 0; nt < 8; ++nt)
        #pragma unroll
        for (int kc = 0; kc < 4; ++kc) {
            const bf16x8 bn = *(const bf16x8*)&Bs[(nt * 16 + ln) * 128 + (((kc * 4 + lg) ^ ln) << 3)];
            acc[nt] = __builtin_amdgcn_mfma_f32_16x16x32_bf16(af[kc], bn, acc[nt], 0, 0, 0);
        }

    const float* bias = (z < 8 ? bq : z < 16 ? bk : bv) + (z & 7) * 128;
    ushort_t* outp = (z < 8 ? Qb : z < 16 ? Kb : Vb);
    const float scale = z < 8 ? 0.08838834764831845f : 1.0f;   // fold 1/sqrt(128) into Q
    const int h = z & 7;
    #pragma unroll
    for (int nt = 0; nt < 8; ++nt) {
        const float bb = bias[nt * 16 + ln];
        #pragma unroll
        for (int j2 = 0; j2 < 4; ++j2) {
            const int r = m0 + w * 16 + lg * 4 + j2;
            const int b = r >> 11, s = r & 2047;
            outp[((size_t)((b << 3) + h) * 2048 + s) * 128 + nt * 16 + ln] =
                f2bf((acc[nt][j2] + bb) * scale);
        }
    }
}

// ============ Kernel 2: flash attention, bf16 MFMA, swizzled LDS, prefetch ============
// grid (32, 16), block 256 (4 waves, 16 q-rows/wave). KV-tile 64.
// Ks double-buffered via global_load_lds (pre-swizzled source); V prefetched to regs,
// transposed+packed into swizzled Vt after barrier (T14). o written bf16.
__global__ __launch_bounds__(256) void attn_kernel(
    const ushort_t* __restrict__ Q, const ushort_t* __restrict__ K,
    const ushort_t* __restrict__ V, ushort_t* __restrict__ O)
{
    __shared__ ushort_t Ks[2][64 * 128];
    __shared__ ushort_t Vt[128 * 64];
    __shared__ ushort_t Ps[64 * 64];

    const int tid = threadIdx.x;
    const int w = tid >> 6, l = tid & 63, lg = l >> 4, ln = l & 15;
    const int bh = blockIdx.y;
    const int q0 = blockIdx.x * 64;
    const size_t base = (size_t)bh * Sq * Hq;
    const ushort_t* Qp = Q + base;
    const ushort_t* Kp = K + base;
    const ushort_t* Vp = V + base;

    bf16x8 qf[4];
    {
        const int qrow = q0 + w * 16 + ln;
        #pragma unroll
        for (int kc = 0; kc < 4; ++kc)
            qf[kc] = *(const bf16x8*)(Qp + (size_t)qrow * Hq + kc * 32 + lg * 8);
    }

    // V staging geometry: thread owns kv pair (kv2,kv2+1) x d-chunks d8 and d8+64
    const int kv2 = (tid & 31) * 2;
    const int d8  = (tid >> 5) * 8;

    f32x4 po[8];
    #pragma unroll
    for (int dt = 0; dt < 8; ++dt) po[dt] = (f32x4){0.f,0.f,0.f,0.f};
    float m_[4], l_[4];
    #pragma unroll
    for (int j = 0; j < 4; ++j) { m_[j] = -1e30f; l_[j] = 0.f; }

    // ---- prologue: stage tile 0 ----
    #pragma unroll
    for (int i = 0; i < 4; ++i) {
        const int seg = w * 4 + i;
        const int row = seg * 4 + (l >> 4);
        const int j = (l & 15) ^ (row & 15);
        GLOAD16(Kp + (size_t)row * Hq + j * 8, &Ks[0][seg * 512]);
    }
    bf16x8 va0 = *(const bf16x8*)(Vp + (size_t)kv2 * Hq + d8);
    bf16x8 va1 = *(const bf16x8*)(Vp + (size_t)(kv2 + 1) * Hq + d8);
    bf16x8 vb0 = *(const bf16x8*)(Vp + (size_t)kv2 * Hq + d8 + 64);
    bf16x8 vb1 = *(const bf16x8*)(Vp + (size_t)(kv2 + 1) * Hq + d8 + 64);
    __syncthreads();
    #pragma unroll
    for (int jj = 0; jj < 8; ++jj) {
        *(uint_t*)&Vt[(d8 + jj) * 64 + (((kv2 >> 3) ^ jj) << 3) + (kv2 & 7)] =
            (uint_t)(ushort_t)va0[jj] | ((uint_t)(ushort_t)va1[jj] << 16);
        *(uint_t*)&Vt[(d8 + 64 + jj) * 64 + (((kv2 >> 3) ^ jj) << 3) + (kv2 & 7)] =
            (uint_t)(ushort_t)vb0[jj] | ((uint_t)(ushort_t)vb1[jj] << 16);
    }
    __syncthreads();

    const int NT = Sq / 64;
    for (int t = 0; t < NT; ++t) {
        const int buf = t & 1;

        // ---- QK^T ----
        f32x4 sa[4];
        #pragma unroll
        for (int ct = 0; ct < 4; ++ct) {
            sa[ct] = (f32x4){0.f,0.f,0.f,0.f};
            #pragma unroll
            for (int kc = 0; kc < 4; ++kc) {
                const bf16x8 bk_ = *(const bf16x8*)&Ks[buf][(ct * 16 + ln) * 128 + (((kc * 4 + lg) ^ ln) << 3)];
                sa[ct] = __builtin_amdgcn_mfma_f32_16x16x32_bf16(qf[kc], bk_, sa[ct], 0, 0, 0);
            }
        }

        // ---- online softmax (lane owns rows lg*4+j, cols ct*16+ln) ----
        float p[4][4], sc[4];
        #pragma unroll
        for (int j = 0; j < 4; ++j) {
            float mx = fmaxf(fmaxf(sa[0][j], sa[1][j]), fmaxf(sa[2][j], sa[3][j]));
            mx = fmaxf(mx, __shfl_xor(mx, 1));
            mx = fmaxf(mx, __shfl_xor(mx, 2));
            mx = fmaxf(mx, __shfl_xor(mx, 4));
            mx = fmaxf(mx, __shfl_xor(mx, 8));
            const float mn = fmaxf(m_[j], mx);
            float r = 0.f;
            #pragma unroll
            for (int ct = 0; ct < 4; ++ct) { p[ct][j] = __expf(sa[ct][j] - mn); r += p[ct][j]; }
            r += __shfl_xor(r, 1); r += __shfl_xor(r, 2);
            r += __shfl_xor(r, 4); r += __shfl_xor(r, 8);
            sc[j] = __expf(m_[j] - mn);
            l_[j] = l_[j] * sc[j] + r;
            m_[j] = mn;
        }

        // ---- prefetch tile t+1 (overlaps with Ps/PV below) ----
        if (t + 1 < NT) {
            const int k0n = (t + 1) * 64;
            #pragma unroll
            for (int i = 0; i < 4; ++i) {
                const int seg = w * 4 + i;
                const int row = seg * 4 + (l >> 4);
                const int j = (l & 15) ^ (row & 15);
                GLOAD16(Kp + (size_t)(k0n + row) * Hq + j * 8, &Ks[buf ^ 1][seg * 512]);
            }
            va0 = *(const bf16x8*)(Vp + (size_t)(k0n + kv2) * Hq + d8);
            va1 = *(const bf16x8*)(Vp + (size_t)(k0n + kv2 + 1) * Hq + d8);
            vb0 = *(const bf16x8*)(Vp + (size_t)(k0n + kv2) * Hq + d8 + 64);
            vb1 = *(const bf16x8*)(Vp + (size_t)(k0n + kv2 + 1) * Hq + d8 + 64);
        }

        // ---- P -> LDS (swizzled; wave-private strip, in-order DS) ----
        #pragma unroll
        for (int ct = 0; ct < 4; ++ct)
            #pragma unroll
            for (int j2 = 0; j2 < 4; ++j2) {
                const int prow = w * 16 + lg * 4 + j2;
                Ps[prow * 64 + (((ct * 2 + (ln >> 3)) ^ (prow & 7)) << 3) + (ln & 7)] = f2bf(p[ct][j2]);
            }

        // rescale O accumulators
        #pragma unroll
        for (int dt = 0; dt < 8; ++dt)
            #pragma unroll
            for (int j2 = 0; j2 < 4; ++j2) po[dt][j2] *= sc[j2];

        // ---- PV ----
        bf16x8 pa[2];
        #pragma unroll
        for (int kc = 0; kc < 2; ++kc)
            pa[kc] = *(const bf16x8*)&Ps[(w * 16 + ln) * 64 + (((kc * 4 + lg) ^ (ln & 7)) << 3)];
        #pragma unroll
        for (int dt = 0; dt < 8; ++dt) {
            #pragma unroll
            for (int kc = 0; kc < 2; ++kc) {
                const bf16x8 bv_ = *(const bf16x8*)&Vt[(dt * 16 + ln) * 64 + (((kc * 4 + lg) ^ (ln & 7)) << 3)];
                po[dt] = __builtin_amdgcn_mfma_f32_16x16x32_bf16(pa[kc], bv_, po[dt], 0, 0, 0);
            }
        }
        __syncthreads();   // PV reads done; prefetched K landed; V regs ready

        if (t + 1 < NT) {
            #pragma unroll
            for (int jj = 0; jj < 8; ++jj) {
                *(uint_t*)&Vt[(d8 + jj) * 64 + (((kv2 >> 3) ^ jj) << 3) + (kv2 & 7)] =
                    (uint_t)(ushort_t)va0[jj] | ((uint_t)(ushort_t)va1[jj] << 16);
                *(uint_t*)&Vt[(d8 + 64 + jj) * 64 + (((kv2 >> 3) ^ jj) << 3) + (kv2 & 7)] =
                    (uint_t)(ushort_t)vb0[jj] | ((uint_t)(ushort_t)vb1[jj] << 16);
            }
        }
        __syncthreads();
    }

    // epilogue: o (bf16) [b*S+q][h*128+d]
    const int b = bh >> 3, h = bh & 7;
    #pragma unroll
    for (int j2 = 0; j2 < 4; ++j2) {
        const float inv = 1.0f / l_[j2];
        const int qrow = q0 + w * 16 + lg * 4 + j2;
        ushort_t* op = O + (size_t)(b * Sq + qrow) * (NHq * Hq) + h * Hq + ln;
        #pragma unroll
        for (int dt = 0; dt < 8; ++dt)
            op[dt * 16] = f2bf(po[dt][j2] * inv);
    }
}

// ============ Kernel 3: unified MFMA GEMM: C[M,N] = A[M,K]@Bt[N,K]^T + bias ============
// grid (M/64, N/128), block 256 (4 waves; wave w owns rows w*16..+15, all 128 cols).
__global__ __launch_bounds__(256) void gemm_kernel(
    const ushort_t* __restrict__ A, const ushort_t* __restrict__ Bt,
    const float* __restrict__ bias, float* __restrict__ Cf, ushort_t* __restrict__ Cb,
    int N, int K, int KS, int relu)
{
    __shared__ ushort_t As[64 * 128];
    __shared__ ushort_t Bs[128 * 128];
    const int tid = threadIdx.x;
    const int w = tid >> 6, l = tid & 63, lg = l >> 4, ln = l & 15;
    const int m0 = blockIdx.x << 6;
    const int n0 = blockIdx.y << 7;

    f32x4 acc[8];
    #pragma unroll
    for (int nt = 0; nt < 8; ++nt) acc[nt] = (f32x4){0.f,0.f,0.f,0.f};

    for (int ks = 0; ks < KS; ++ks) {
        const int k0 = ks << 7;
        #pragma unroll
        for (int i = 0; i < 4; ++i) {
            const int seg = w * 4 + i;
            const int row = seg * 4 + (l >> 4);
            const int j = (l & 15) ^ (row & 15);
            GLOAD16(A + (size_t)(m0 + row) * K + k0 + j * 8, &As[seg * 512]);
        }
        #pragma unroll
        for (int i = 0; i < 8; ++i) {
            const int seg = w * 8 + i;
            const int row = seg * 4 + (l >> 4);
            const int j = (l & 15) ^ (row & 15);
            GLOAD16(Bt + (size_t)(n0 + row) * K + k0 + j * 8, &Bs[seg * 512]);
        }
        __syncthreads();

        bf16x8 af[4];
        #pragma unroll
        for (int kc = 0; kc < 4; ++kc)
            af[kc] = *(const bf16x8*)&As[(w * 16 + ln) * 128 + (((kc * 4 + lg) ^ ln) << 3)];
        #pragma unroll
        for (int nt = 0; nt < 8; ++nt)
            #pragma unroll
            for (int kc = 0; kc < 4; ++kc) {
                const bf16x8 bn = *(const bf16x8*)&Bs[(nt * 16 + ln) * 128 + (((kc * 4 + lg) ^ ln) << 3)];
                acc[nt] = __builtin_amdgcn_mfma_f32_16x16x32_bf16(af[kc], bn, acc[nt], 0, 0, 0);
            }
        __syncthreads();
    }

    #pragma unroll
    for (int nt = 0; nt < 8; ++nt) {
        const int col = n0 + nt * 16 + ln;
        const float bb = bias[col];
        #pragma unroll
        for (int j2 = 0; j2 < 4; ++j2) {
            const int r = m0 + w * 16 + lg * 4 + j2;
            float v = acc[nt][j2] + bb;
            if (relu) v = fmaxf(v, 0.f);
            if (Cb) Cb[(size_t)r * N + col] = f2bf(v);
            else    Cf[(size_t)r * N + col] = v;
        }
    }
}

// ============ LayerNorm (optional residual, optional bf16 copy of output) ============
__global__ __launch_bounds__(256) void ln_kernel(
    const float* __restrict__ in, const float* __restrict__ res,
    const float* __restrict__ g, const float* __restrict__ bta,
    float* __restrict__ out, ushort_t* __restrict__ out_bf)
{
    const int lane = threadIdx.x & 63;
    const int row  = (blockIdx.x << 2) + (threadIdx.x >> 6);
    const int base = row * 128 + lane * 2;
    float2 v = *(const float2*)&in[base];
    if (res) {
        const float2 rv = *(const float2*)&res[base];
        v.x += rv.x; v.y += rv.y;
    }
    float s  = v.x + v.y;
    float sq = v.x * v.x + v.y * v.y;
    #pragma unroll
    for (int mm = 1; mm <= 32; mm <<= 1) {
        s  += __shfl_xor(s, mm);
        sq += __shfl_xor(sq, mm);
    }
    const float mean = s * (1.0f / 128.0f);
    const float var  = sq * (1.0f / 128.0f) - mean * mean;
    const float rstd = rsqrtf(var + 1e-5f);
    const float2 gv = *(const float2*)&g[lane * 2];
    const float2 bv = *(const float2*)&bta[lane * 2];
    float2 o;
    o.x = (v.x - mean) * rstd * gv.x + bv.x;
    o.y = (v.y - mean) * rstd * gv.y + bv.y;
    *(float2*)&out[base] = o;
    if (out_bf) {
        const uint_t pk = (uint_t)f2bf(o.x) | ((uint_t)f2bf(o.y) << 16);
        *(uint_t*)&out_bf[base] = pk;
    }
}

extern "C" void kernel_launch(void* const* d_in, const int* in_sizes, int n_in,
                              void* d_out, int out_size, void* d_ws, size_t ws_size,
                              hipStream_t stream)
{
    const float* x   = (const float*)d_in[0];
    const float* Wq  = (const float*)d_in[1];
    const float* bq  = (const float*)d_in[2];
    const float* Wk  = (const float*)d_in[3];
    const float* bk  = (const float*)d_in[4];
    const float* Wv  = (const float*)d_in[5];
    const float* bv  = (const float*)d_in[6];
    const float* Wo  = (const float*)d_in[7];
    const float* bo  = (const float*)d_in[8];
    const float* W1  = (const float*)d_in[9];
    const float* b1  = (const float*)d_in[10];
    const float* W2  = (const float*)d_in[11];
    const float* b2  = (const float*)d_in[12];
    const float* g1  = (const float*)d_in[13];
    const float* be1 = (const float*)d_in[14];
    const float* g2  = (const float*)d_in[15];
    const float* be2 = (const float*)d_in[16];
    (void)in_sizes; (void)n_in; (void)out_size; (void)ws_size;

    // workspace layout (ushort elems)
    ushort_t* Wt_all = (ushort_t*)d_ws;              // 24*16384 = 393216
    ushort_t* Wot = Wt_all + 393216;                 // 128*1024
    ushort_t* W1t = Wot + 131072;                    // 256*128
    ushort_t* W2t = W1t + 32768;                     // 128*256
    ushort_t* Qb  = W2t + 32768;                     // 4194304 each
    ushort_t* Kb  = Qb + 4194304;
    ushort_t* Vb  = Kb + 4194304;
    ushort_t* ob  = Vb + 4194304;                    // 4096x1024 bf16
    ushort_t* yb  = ob + 4194304;                    // 4096x128 bf16
    ushort_t* h1  = yb + 524288;                     // 4096x256 bf16
    float* y0 = (float*)(h1 + 1048576);              // 4096x128 f32
    float* y  = y0 + 524288;
    float* f  = y  + 524288;

    tw_kernel  <<<dim3(128, 27),  256, 0, stream>>>(Wq, Wk, Wv, Wo, W1, W2, Wt_all, Wot, W1t, W2t);
    qkv_gemm   <<<dim3(64, 24),   256, 0, stream>>>(x, Wt_all, bq, bk, bv, Qb, Kb, Vb);
    attn_kernel<<<dim3(32, 16),   256, 0, stream>>>(Qb, Kb, Vb, ob);
    gemm_kernel<<<dim3(64, 1),    256, 0, stream>>>(ob, Wot, bo, y0, nullptr, 128, 1024, 8, 0);
    ln_kernel  <<<1024,           256, 0, stream>>>(y0, nullptr, g1, be1, y, yb);
    gemm_kernel<<<dim3(64, 2),    256, 0, stream>>>(yb, W1t, b1, nullptr, h1, 256, 128, 1, 1);
    gemm_kernel<<<dim3(64, 1),    256, 0, stream>>>(h1, W2t, b2, f, nullptr, 128, 256, 2, 1);
    ln_kernel  <<<1024,           256, 0, stream>>>(y, f, g2, be2, (float*)d_out, nullptr);
}

// Round 4
// 121.465 us; speedup vs baseline: 9.5170x; 1.2288x over previous
//
#include <hip/hip_runtime.h>
#include <math.h>

#define Bq  2
#define Sq  2048
#define Hq  128
#define NHq 8

typedef __attribute__((ext_vector_type(8))) short bf16x8;
typedef __attribute__((ext_vector_type(4))) float f32x4;
typedef __attribute__((ext_vector_type(16))) float f32x16;
typedef __attribute__((ext_vector_type(4))) unsigned short ushort4_t;
typedef __attribute__((ext_vector_type(4))) unsigned int uint4v;
typedef unsigned short ushort_t;
typedef unsigned int uint_t;

__device__ inline ushort_t f2bf(float f) {
    union { float f; uint_t u; } c; c.f = f;
    uint_t u = c.u + 0x7FFFu + ((c.u >> 16) & 1u);   // RNE
    return (ushort_t)(u >> 16);
}

__device__ inline uint_t cvtpk_bf16(float lo, float hi) {
    uint_t r;
    asm("v_cvt_pk_bf16_f32 %0, %1, %2" : "=v"(r) : "v"(lo), "v"(hi));
    return r;
}
// exchanges a[32:63] <-> b[0:31]
__device__ inline void pswap32(uint_t &a, uint_t &b) {
    asm("v_permlane32_swap_b32 %0, %1" : "+v"(a), "+v"(b));
}

// async global->LDS, 16B per lane; LDS dest = wave-uniform base + lane*16
#define GLOAD16(gsrc, ldst) \
    __builtin_amdgcn_global_load_lds( \
        (const __attribute__((address_space(1))) unsigned int*)(const void*)(gsrc), \
        (__attribute__((address_space(3))) unsigned int*)(ldst), 16, 0, 0)

// ============ Kernel 0: weight transpose + bf16 convert ============
__global__ __launch_bounds__(256) void tw_kernel(
    const float* __restrict__ Wq, const float* __restrict__ Wk, const float* __restrict__ Wv,
    const float* __restrict__ Wo, const float* __restrict__ W1, const float* __restrict__ W2,
    ushort_t* __restrict__ Wt_all, ushort_t* __restrict__ Wot,
    ushort_t* __restrict__ W1t, ushort_t* __restrict__ W2t)
{
    const int z = blockIdx.y;
    const float* src; ushort_t* dst; int R, C;
    if (z < 24) { const int h = z & 7;
        src = (z < 8 ? Wq : z < 16 ? Wk : Wv) + h * 16384;
        dst = Wt_all + z * 16384; R = 128; C = 128;
    } else if (z == 24) { src = Wo; dst = Wot; R = 1024; C = 128; }
    else if (z == 25)   { src = W1; dst = W1t; R = 128;  C = 256; }
    else                { src = W2; dst = W2t; R = 256;  C = 128; }

    const int tpc = C >> 5;
    if ((int)blockIdx.x >= (R >> 5) * tpc) return;
    const int r0 = (blockIdx.x / tpc) << 5;
    const int c0 = (blockIdx.x % tpc) << 5;

    __shared__ float ls[32][33];
    const int t = threadIdx.x;
    const int lr = t >> 5, lc = t & 31;
    #pragma unroll
    for (int i = 0; i < 4; ++i)
        ls[lr + i * 8][lc] = src[(size_t)(r0 + lr + i * 8) * C + c0 + lc];
    __syncthreads();
    const int wc = t >> 3, wr0 = (t & 7) << 2;
    ushort4_t o4;
    o4[0] = f2bf(ls[wr0 + 0][wc]); o4[1] = f2bf(ls[wr0 + 1][wc]);
    o4[2] = f2bf(ls[wr0 + 2][wc]); o4[3] = f2bf(ls[wr0 + 3][wc]);
    *(ushort4_t*)&dst[(size_t)(c0 + wc) * R + r0 + wr0] = o4;
}

// ============ Kernel 1: batched QKV projection, MFMA ============
__global__ __launch_bounds__(256) void qkv_gemm(
    const float* __restrict__ x, const ushort_t* __restrict__ Wt_all,
    const float* __restrict__ bq, const float* __restrict__ bk, const float* __restrict__ bv,
    ushort_t* __restrict__ Qb, ushort_t* __restrict__ Kb, ushort_t* __restrict__ Vb)
{
    __shared__ ushort_t As[64 * 128];
    __shared__ ushort_t Bs[128 * 128];
    const int tid = threadIdx.x;
    const int w = tid >> 6, l = tid & 63, lg = l >> 4, ln = l & 15;
    const int m0 = blockIdx.x << 6;
    const int z  = blockIdx.y;

    #pragma unroll
    for (int i = 0; i < 4; ++i) {
        const int c = tid + i * 256;
        const int row = c >> 4, j = c & 15;
        const float* xp = x + (size_t)(m0 + row) * 128 + j * 8;
        const float4 a = *(const float4*)xp;
        const float4 b = *(const float4*)(xp + 4);
        bf16x8 v;
        v[0]=f2bf(a.x); v[1]=f2bf(a.y); v[2]=f2bf(a.z); v[3]=f2bf(a.w);
        v[4]=f2bf(b.x); v[5]=f2bf(b.y); v[6]=f2bf(b.z); v[7]=f2bf(b.w);
        *(bf16x8*)&As[row * 128 + ((j ^ (row & 15)) << 3)] = v;
    }
    const ushort_t* Wz = Wt_all + (size_t)z * 16384;
    #pragma unroll
    for (int i = 0; i < 8; ++i) {
        const int seg = w * 8 + i;
        const int row = seg * 4 + (l >> 4);
        const int j = (l & 15) ^ (row & 15);
        GLOAD16(Wz + row * 128 + j * 8, &Bs[seg * 512]);
    }
    __syncthreads();

    bf16x8 af[4];
    #pragma unroll
    for (int kc = 0; kc < 4; ++kc)
        af[kc] = *(const bf16x8*)&As[(w * 16 + ln) * 128 + (((kc * 4 + lg) ^ ln) << 3)];

    f32x4 acc[8];
    #pragma unroll
    for (int nt = 0; nt < 8; ++nt) acc[nt] = (f32x4){0.f,0.f,0.f,0.f};
    #pragma unroll
    for (int nt = 0; nt < 8; ++nt)
        #pragma unroll
        for (int kc = 0; kc < 4; ++kc) {
            const bf16x8 bn = *(const bf16x8*)&Bs[(nt * 16 + ln) * 128 + (((kc * 4 + lg) ^ ln) << 3)];
            acc[nt] = __builtin_amdgcn_mfma_f32_16x16x32_bf16(af[kc], bn, acc[nt], 0, 0, 0);
        }

    const float* bias = (z < 8 ? bq : z < 16 ? bk : bv) + (z & 7) * 128;
    ushort_t* outp = (z < 8 ? Qb : z < 16 ? Kb : Vb);
    const float scale = z < 8 ? 0.08838834764831845f : 1.0f;
    const int h = z & 7;
    #pragma unroll
    for (int nt = 0; nt < 8; ++nt) {
        const float bb = bias[nt * 16 + ln];
        #pragma unroll
        for (int j2 = 0; j2 < 4; ++j2) {
            const int r = m0 + w * 16 + lg * 4 + j2;
            const int b = r >> 11, s = r & 2047;
            outp[((size_t)((b << 3) + h) * 2048 + s) * 128 + nt * 16 + ln] =
                f2bf((acc[nt][j2] + bb) * scale);
        }
    }
}

// ============ Kernel 2: flash attention v3 ============
// grid 256 (XCD-chunked), block 256 = 4 waves; wave owns 32 q-rows; KV-tile 64.
// Swapped QK^T: S^T = mfma(A=K_frag, B=Q_frag) -> lane owns 1 q-col, 32 kv in regs
// (rows (reg&3)+8*(reg>>2)+4*(lane>>5) per 32-kv tile). In-lane softmax.
// P -> PV B-frag via v_cvt_pk_bf16_f32 + v_permlane32_swap (no LDS round trip).
// PV: O^T = mfma(A=Vt rows, B=P). Epilogue: O^T -> LDS bounce -> coalesced stores.
__global__ __launch_bounds__(256, 1) void attn_kernel(
    const ushort_t* __restrict__ Q, const ushort_t* __restrict__ K,
    const ushort_t* __restrict__ V, ushort_t* __restrict__ O)
{
    __shared__ ushort_t Ks[2][64 * 128];
    __shared__ ushort_t Vt[128 * 64];

    const int tid = threadIdx.x;
    const int w = tid >> 6, l = tid & 63;
    const int ln5 = l & 31, h5 = l >> 5;

    const int id  = blockIdx.x;
    const int id2 = (id & 7) * 32 + (id >> 3);   // 8 XCDs x 32-chunk, bijective (256 blocks)
    const int bh  = id2 >> 4;
    const int q0  = (id2 & 15) << 7;             // 128 q-rows per block

    const size_t base = (size_t)bh * Sq * Hq;
    const ushort_t* Qp = Q + base;
    const ushort_t* Kp = K + base;
    const ushort_t* Vp = V + base;

    // Q as B-frags: col n = q = ln5, k = kc*16 + h5*8 + j
    bf16x8 qf[8];
    {
        const ushort_t* qrow = Qp + (size_t)(q0 + w * 32 + ln5) * Hq;
        #pragma unroll
        for (int kc = 0; kc < 8; ++kc)
            qf[kc] = *(const bf16x8*)(qrow + kc * 16 + h5 * 8);
    }

    const int kv2 = (tid & 31) * 2;
    const int d8  = (tid >> 5) * 8;

    f32x16 po[4];
    #pragma unroll
    for (int dt = 0; dt < 4; ++dt)
        #pragma unroll
        for (int r = 0; r < 16; ++r) po[dt][r] = 0.f;
    float m_ = -1e30f, l_ = 0.f;

    // ---- prologue: stage tile 0 ----
    #pragma unroll
    for (int i = 0; i < 4; ++i) {
        const int seg = w * 4 + i;
        const int row = seg * 4 + (l >> 4);
        const int j = (l & 15) ^ (row & 15);
        GLOAD16(Kp + (size_t)row * Hq + j * 8, &Ks[0][seg * 512]);
    }
    bf16x8 va0 = *(const bf16x8*)(Vp + (size_t)kv2 * Hq + d8);
    bf16x8 va1 = *(const bf16x8*)(Vp + (size_t)(kv2 + 1) * Hq + d8);
    bf16x8 vb0 = *(const bf16x8*)(Vp + (size_t)kv2 * Hq + d8 + 64);
    bf16x8 vb1 = *(const bf16x8*)(Vp + (size_t)(kv2 + 1) * Hq + d8 + 64);
    __syncthreads();
    #pragma unroll
    for (int jj = 0; jj < 8; ++jj) {
        *(uint_t*)&Vt[(d8 + jj) * 64 + (((kv2 >> 3) ^ jj) << 3) + (kv2 & 7)] =
            (uint_t)(ushort_t)va0[jj] | ((uint_t)(ushort_t)va1[jj] << 16);
        *(uint_t*)&Vt[(d8 + 64 + jj) * 64 + (((kv2 >> 3) ^ jj) << 3) + (kv2 & 7)] =
            (uint_t)(ushort_t)vb0[jj] | ((uint_t)(ushort_t)vb1[jj] << 16);
    }
    __syncthreads();

    const int NT = Sq / 64;
    for (int t = 0; t < NT; ++t) {
        const int buf = t & 1;

        // ---- QK^T (S^T = K . Q^T) ----
        f32x16 st[2];
        #pragma unroll
        for (int mt = 0; mt < 2; ++mt)
            #pragma unroll
            for (int r = 0; r < 16; ++r) st[mt][r] = 0.f;

        __builtin_amdgcn_s_setprio(1);
        #pragma unroll
        for (int kc = 0; kc < 8; ++kc) {
            #pragma unroll
            for (int mt = 0; mt < 2; ++mt) {
                const int row = mt * 32 + ln5;
                const int slot = (kc * 2 + h5) ^ (row & 15);
                const bf16x8 ka = *(const bf16x8*)&Ks[buf][row * 128 + (slot << 3)];
                st[mt] = __builtin_amdgcn_mfma_f32_32x32x16_bf16(ka, qf[kc], st[mt], 0, 0, 0);
            }
        }
        __builtin_amdgcn_s_setprio(0);

        // ---- prefetch tile t+1 (in flight through softmax+PV) ----
        if (t + 1 < NT) {
            const int k0n = (t + 1) * 64;
            #pragma unroll
            for (int i = 0; i < 4; ++i) {
                const int seg = w * 4 + i;
                const int row = seg * 4 + (l >> 4);
                const int j = (l & 15) ^ (row & 15);
                GLOAD16(Kp + (size_t)(k0n + row) * Hq + j * 8, &Ks[buf ^ 1][seg * 512]);
            }
            va0 = *(const bf16x8*)(Vp + (size_t)(k0n + kv2) * Hq + d8);
            va1 = *(const bf16x8*)(Vp + (size_t)(k0n + kv2 + 1) * Hq + d8);
            vb0 = *(const bf16x8*)(Vp + (size_t)(k0n + kv2) * Hq + d8 + 64);
            vb1 = *(const bf16x8*)(Vp + (size_t)(k0n + kv2 + 1) * Hq + d8 + 64);
        }

        // ---- in-lane online softmax (1 q-col, 32 kv per lane) ----
        float mxv[16];
        #pragma unroll
        for (int r = 0; r < 16; ++r) mxv[r] = fmaxf(st[0][r], st[1][r]);
        #pragma unroll
        for (int sd = 8; sd >= 1; sd >>= 1)
            #pragma unroll
            for (int i = 0; i < sd; ++i) mxv[i] = fmaxf(mxv[i], mxv[i + sd]);
        float mx = mxv[0];
        mx = fmaxf(mx, __shfl_xor(mx, 32));
        const float mn = fmaxf(m_, mx);

        float pe[32];
        #pragma unroll
        for (int mt = 0; mt < 2; ++mt)
            #pragma unroll
            for (int r = 0; r < 16; ++r)
                pe[mt * 16 + r] = __expf(st[mt][r] - mn);

        float sv[16];
        #pragma unroll
        for (int r = 0; r < 16; ++r) sv[r] = pe[r] + pe[16 + r];
        #pragma unroll
        for (int sd = 8; sd >= 1; sd >>= 1)
            #pragma unroll
            for (int i = 0; i < sd; ++i) sv[i] += sv[i + sd];
        float rs = sv[0];
        rs += __shfl_xor(rs, 32);

        const float sc = __expf(m_ - mn);   // first tile: exp(-1e30) = 0
        l_ = l_ * sc + rs;
        m_ = mn;

        // ---- P -> PV B-frags via cvt_pk + permlane32_swap (T12) ----
        bf16x8 pb[4];
        #pragma unroll
        for (int ks = 0; ks < 4; ++ks) {
            const int o = (ks >> 1) * 16 + (ks & 1) * 8;
            uint_t wA = cvtpk_bf16(pe[o + 0], pe[o + 1]);
            uint_t wB = cvtpk_bf16(pe[o + 4], pe[o + 5]);
            pswap32(wA, wB);                 // wA = words(j0,j1), wB = words(j4,j5)
            uint_t wC = cvtpk_bf16(pe[o + 2], pe[o + 3]);
            uint_t wD = cvtpk_bf16(pe[o + 6], pe[o + 7]);
            pswap32(wC, wD);                 // wC = words(j2,j3), wD = words(j6,j7)
            uint4v wv; wv[0] = wA; wv[1] = wC; wv[2] = wB; wv[3] = wD;
            pb[ks] = __builtin_bit_cast(bf16x8, wv);
        }

        // ---- rescale O^T (uniform per lane) ----
        #pragma unroll
        for (int dt = 0; dt < 4; ++dt)
            #pragma unroll
            for (int r = 0; r < 16; ++r) po[dt][r] *= sc;

        // ---- PV: O^T = V^T . P^T ----
        __builtin_amdgcn_s_setprio(1);
        #pragma unroll
        for (int dt = 0; dt < 4; ++dt) {
            #pragma unroll
            for (int ks = 0; ks < 4; ++ks) {
                const int row = dt * 32 + ln5;
                const int slot = (ks * 2 + h5) ^ (row & 7);
                const bf16x8 va = *(const bf16x8*)&Vt[row * 64 + (slot << 3)];
                po[dt] = __builtin_amdgcn_mfma_f32_32x32x16_bf16(va, pb[ks], po[dt], 0, 0, 0);
            }
        }
        __builtin_amdgcn_s_setprio(0);

        __syncthreads();   // PV reads done; prefetched K landed; V regs ready
        if (t + 1 < NT) {
            #pragma unroll
            for (int jj = 0; jj < 8; ++jj) {
                *(uint_t*)&Vt[(d8 + jj) * 64 + (((kv2 >> 3) ^ jj) << 3) + (kv2 & 7)] =
                    (uint_t)(ushort_t)va0[jj] | ((uint_t)(ushort_t)va1[jj] << 16);
                *(uint_t*)&Vt[(d8 + 64 + jj) * 64 + (((kv2 >> 3) ^ jj) << 3) + (kv2 & 7)] =
                    (uint_t)(ushort_t)vb0[jj] | ((uint_t)(ushort_t)vb1[jj] << 16);
            }
        }
        __syncthreads();
    }

    // ---- epilogue: O^T -> LDS bounce -> coalesced bf16 stores ----
    const float inv = 1.0f / l_;
    const int b = bh >> 3, h = bh & 7;
    ushort_t* Lw = &Ks[0][0] + w * 4096;   // 32 q-rows x 128 d, wave-private
    #pragma unroll
    for (int dt = 0; dt < 4; ++dt)
        #pragma unroll
        for (int r = 0; r < 16; r += 2) {
            const int d = dt * 32 + (r & 3) + 8 * (r >> 2) + 4 * h5;
            const uint_t pk = cvtpk_bf16(po[dt][r] * inv, po[dt][r + 1] * inv);
            *(uint_t*)&Lw[ln5 * 128 + d] = pk;
        }
    #pragma unroll
    for (int rb = 0; rb < 8; ++rb) {
        const int qr = rb * 4 + (l >> 4);
        const bf16x8 vv = *(const bf16x8*)&Lw[qr * 128 + (l & 15) * 8];
        *(bf16x8*)(O + (size_t)(b * Sq + q0 + w * 32 + qr) * (NHq * Hq) + h * Hq + (l & 15) * 8) = vv;
    }
}

// ============ Kernel 3: unified MFMA GEMM: C[M,N] = A[M,K]@Bt[N,K]^T + bias ============
__global__ __launch_bounds__(256) void gemm_kernel(
    const ushort_t* __restrict__ A, const ushort_t* __restrict__ Bt,
    const float* __restrict__ bias, float* __restrict__ Cf, ushort_t* __restrict__ Cb,
    int N, int K, int KS, int relu)
{
    __shared__ ushort_t As[64 * 128];
    __shared__ ushort_t Bs[128 * 128];
    const int tid = threadIdx.x;
    const int w = tid >> 6, l = tid & 63, lg = l >> 4, ln = l & 15;
    const int m0 = blockIdx.x << 6;
    const int n0 = blockIdx.y << 7;

    f32x4 acc[8];
    #pragma unroll
    for (int nt = 0; nt < 8; ++nt) acc[nt] = (f32x4){0.f,0.f,0.f,0.f};

    for (int ks = 0; ks < KS; ++ks) {
        const int k0 = ks << 7;
        #pragma unroll
        for (int i = 0; i < 4; ++i) {
            const int seg = w * 4 + i;
            const int row = seg * 4 + (l >> 4);
            const int j = (l & 15) ^ (row & 15);
            GLOAD16(A + (size_t)(m0 + row) * K + k0 + j * 8, &As[seg * 512]);
        }
        #pragma unroll
        for (int i = 0; i < 8; ++i) {
            const int seg = w * 8 + i;
            const int row = seg * 4 + (l >> 4);
            const int j = (l & 15) ^ (row & 15);
            GLOAD16(Bt + (size_t)(n0 + row) * K + k0 + j * 8, &Bs[seg * 512]);
        }
        __syncthreads();

        bf16x8 af[4];
        #pragma unroll
        for (int kc = 0; kc < 4; ++kc)
            af[kc] = *(const bf16x8*)&As[(w * 16 + ln) * 128 + (((kc * 4 + lg) ^ ln) << 3)];
        #pragma unroll
        for (int nt = 0; nt < 8; ++nt)
            #pragma unroll
            for (int kc = 0; kc < 4; ++kc) {
                const bf16x8 bn = *(const bf16x8*)&Bs[(nt * 16 + ln) * 128 + (((kc * 4 + lg) ^ ln) << 3)];
                acc[nt] = __builtin_amdgcn_mfma_f32_16x16x32_bf16(af[kc], bn, acc[nt], 0, 0, 0);
            }
        __syncthreads();
    }

    #pragma unroll
    for (int nt = 0; nt < 8; ++nt) {
        const int col = n0 + nt * 16 + ln;
        const float bb = bias[col];
        #pragma unroll
        for (int j2 = 0; j2 < 4; ++j2) {
            const int r = m0 + w * 16 + lg * 4 + j2;
            float v = acc[nt][j2] + bb;
            if (relu) v = fmaxf(v, 0.f);
            if (Cb) Cb[(size_t)r * N + col] = f2bf(v);
            else    Cf[(size_t)r * N + col] = v;
        }
    }
}

// ============ LayerNorm (optional residual, optional bf16 copy) ============
__global__ __launch_bounds__(256) void ln_kernel(
    const float* __restrict__ in, const float* __restrict__ res,
    const float* __restrict__ g, const float* __restrict__ bta,
    float* __restrict__ out, ushort_t* __restrict__ out_bf)
{
    const int lane = threadIdx.x & 63;
    const int row  = (blockIdx.x << 2) + (threadIdx.x >> 6);
    const int base = row * 128 + lane * 2;
    float2 v = *(const float2*)&in[base];
    if (res) {
        const float2 rv = *(const float2*)&res[base];
        v.x += rv.x; v.y += rv.y;
    }
    float s  = v.x + v.y;
    float sq = v.x * v.x + v.y * v.y;
    #pragma unroll
    for (int mm = 1; mm <= 32; mm <<= 1) {
        s  += __shfl_xor(s, mm);
        sq += __shfl_xor(sq, mm);
    }
    const float mean = s * (1.0f / 128.0f);
    const float var  = sq * (1.0f / 128.0f) - mean * mean;
    const float rstd = rsqrtf(var + 1e-5f);
    const float2 gv = *(const float2*)&g[lane * 2];
    const float2 bv = *(const float2*)&bta[lane * 2];
    float2 o;
    o.x = (v.x - mean) * rstd * gv.x + bv.x;
    o.y = (v.y - mean) * rstd * gv.y + bv.y;
    *(float2*)&out[base] = o;
    if (out_bf) {
        const uint_t pk = (uint_t)f2bf(o.x) | ((uint_t)f2bf(o.y) << 16);
        *(uint_t*)&out_bf[base] = pk;
    }
}

extern "C" void kernel_launch(void* const* d_in, const int* in_sizes, int n_in,
                              void* d_out, int out_size, void* d_ws, size_t ws_size,
                              hipStream_t stream)
{
    const float* x   = (const float*)d_in[0];
    const float* Wq  = (const float*)d_in[1];
    const float* bq  = (const float*)d_in[2];
    const float* Wk  = (const float*)d_in[3];
    const float* bk  = (const float*)d_in[4];
    const float* Wv  = (const float*)d_in[5];
    const float* bv  = (const float*)d_in[6];
    const float* Wo  = (const float*)d_in[7];
    const float* bo  = (const float*)d_in[8];
    const float* W1  = (const float*)d_in[9];
    const float* b1  = (const float*)d_in[10];
    const float* W2  = (const float*)d_in[11];
    const float* b2  = (const float*)d_in[12];
    const float* g1  = (const float*)d_in[13];
    const float* be1 = (const float*)d_in[14];
    const float* g2  = (const float*)d_in[15];
    const float* be2 = (const float*)d_in[16];
    (void)in_sizes; (void)n_in; (void)out_size; (void)ws_size;

    ushort_t* Wt_all = (ushort_t*)d_ws;              // 24*16384
    ushort_t* Wot = Wt_all + 393216;
    ushort_t* W1t = Wot + 131072;
    ushort_t* W2t = W1t + 32768;
    ushort_t* Qb  = W2t + 32768;
    ushort_t* Kb  = Qb + 4194304;
    ushort_t* Vb  = Kb + 4194304;
    ushort_t* ob  = Vb + 4194304;                    // 4096x1024 bf16
    ushort_t* yb  = ob + 4194304;
    ushort_t* h1  = yb + 524288;
    float* y0 = (float*)(h1 + 1048576);
    float* y  = y0 + 524288;
    float* f  = y  + 524288;

    tw_kernel  <<<dim3(128, 27),  256, 0, stream>>>(Wq, Wk, Wv, Wo, W1, W2, Wt_all, Wot, W1t, W2t);
    qkv_gemm   <<<dim3(64, 24),   256, 0, stream>>>(x, Wt_all, bq, bk, bv, Qb, Kb, Vb);
    attn_kernel<<<dim3(256),      256, 0, stream>>>(Qb, Kb, Vb, ob);
    gemm_kernel<<<dim3(64, 1),    256, 0, stream>>>(ob, Wot, bo, y0, nullptr, 128, 1024, 8, 0);
    ln_kernel  <<<1024,           256, 0, stream>>>(y0, nullptr, g1, be1, y, yb);
    gemm_kernel<<<dim3(64, 2),    256, 0, stream>>>(yb, W1t, b1, nullptr, h1, 256, 128, 1, 1);
    gemm_kernel<<<dim3(64, 1),    256, 0, stream>>>(h1, W2t, b2, f, nullptr, 128, 256, 2, 1);
    ln_kernel  <<<1024,           256, 0, stream>>>(y, f, g2, be2, (float*)d_out, nullptr);
}

// Round 5
// 95.875 us; speedup vs baseline: 12.0572x; 1.2669x over previous
//
#include <hip/hip_runtime.h>
#include <math.h>

#define Bq  2
#define Sq  2048
#define Hq  128
#define NHq 8

typedef __attribute__((ext_vector_type(8))) short bf16x8;
typedef __attribute__((ext_vector_type(4))) float f32x4;
typedef __attribute__((ext_vector_type(16))) float f32x16;
typedef __attribute__((ext_vector_type(4))) unsigned short ushort4_t;
typedef __attribute__((ext_vector_type(4))) unsigned int uint4v;
typedef __attribute__((ext_vector_type(2))) unsigned long long u64x2;
typedef unsigned short ushort_t;
typedef unsigned int uint_t;
typedef unsigned long long u64;

__device__ inline ushort_t f2bf(float f) {
    union { float f; uint_t u; } c; c.f = f;
    uint_t u = c.u + 0x7FFFu + ((c.u >> 16) & 1u);   // RNE
    return (ushort_t)(u >> 16);
}
__device__ inline float bf2f(ushort_t u) {
    union { uint_t u; float f; } c; c.u = ((uint_t)u) << 16;
    return c.f;
}

__device__ inline uint_t cvtpk_bf16(float lo, float hi) {
    uint_t r;
    asm("v_cvt_pk_bf16_f32 %0, %1, %2" : "=v"(r) : "v"(lo), "v"(hi));
    return r;
}
// exchanges a[32:63] <-> b[0:31]
__device__ inline void pswap32(uint_t &a, uint_t &b) {
    asm("v_permlane32_swap_b32 %0, %1" : "+v"(a), "+v"(b));
}

// async global->LDS, 16B per lane; LDS dest = wave-uniform base + lane*16
#define GLOAD16(gsrc, ldst) \
    __builtin_amdgcn_global_load_lds( \
        (const __attribute__((address_space(1))) unsigned int*)(const void*)(gsrc), \
        (__attribute__((address_space(3))) unsigned int*)(ldst), 16, 0, 0)

// ============ Kernel 0: weight transpose + bf16 convert ============
__global__ __launch_bounds__(256) void tw_kernel(
    const float* __restrict__ Wq, const float* __restrict__ Wk, const float* __restrict__ Wv,
    const float* __restrict__ Wo, const float* __restrict__ W1, const float* __restrict__ W2,
    ushort_t* __restrict__ Wt_all, ushort_t* __restrict__ Wot,
    ushort_t* __restrict__ W1t, ushort_t* __restrict__ W2t)
{
    const int z = blockIdx.y;
    const float* src; ushort_t* dst; int R, C;
    if (z < 24) { const int h = z & 7;
        src = (z < 8 ? Wq : z < 16 ? Wk : Wv) + h * 16384;
        dst = Wt_all + z * 16384; R = 128; C = 128;
    } else if (z == 24) { src = Wo; dst = Wot; R = 1024; C = 128; }
    else if (z == 25)   { src = W1; dst = W1t; R = 128;  C = 256; }
    else                { src = W2; dst = W2t; R = 256;  C = 128; }

    const int tpc = C >> 5;
    if ((int)blockIdx.x >= (R >> 5) * tpc) return;
    const int r0 = (blockIdx.x / tpc) << 5;
    const int c0 = (blockIdx.x % tpc) << 5;

    __shared__ float ls[32][33];
    const int t = threadIdx.x;
    const int lr = t >> 5, lc = t & 31;
    #pragma unroll
    for (int i = 0; i < 4; ++i)
        ls[lr + i * 8][lc] = src[(size_t)(r0 + lr + i * 8) * C + c0 + lc];
    __syncthreads();
    const int wc = t >> 3, wr0 = (t & 7) << 2;
    ushort4_t o4;
    o4[0] = f2bf(ls[wr0 + 0][wc]); o4[1] = f2bf(ls[wr0 + 1][wc]);
    o4[2] = f2bf(ls[wr0 + 2][wc]); o4[3] = f2bf(ls[wr0 + 3][wc]);
    *(ushort4_t*)&dst[(size_t)(c0 + wc) * R + r0 + wr0] = o4;
}

// ============ Kernel 1: batched QKV projection, MFMA ============
__global__ __launch_bounds__(256) void qkv_gemm(
    const float* __restrict__ x, const ushort_t* __restrict__ Wt_all,
    const float* __restrict__ bq, const float* __restrict__ bk, const float* __restrict__ bv,
    ushort_t* __restrict__ Qb, ushort_t* __restrict__ Kb, ushort_t* __restrict__ Vb)
{
    __shared__ ushort_t As[64 * 128];
    __shared__ ushort_t Bs[128 * 128];
    const int tid = threadIdx.x;
    const int w = tid >> 6, l = tid & 63, lg = l >> 4, ln = l & 15;
    const int m0 = blockIdx.x << 6;
    const int z  = blockIdx.y;

    #pragma unroll
    for (int i = 0; i < 4; ++i) {
        const int c = tid + i * 256;
        const int row = c >> 4, j = c & 15;
        const float* xp = x + (size_t)(m0 + row) * 128 + j * 8;
        const float4 a = *(const float4*)xp;
        const float4 b = *(const float4*)(xp + 4);
        bf16x8 v;
        v[0]=f2bf(a.x); v[1]=f2bf(a.y); v[2]=f2bf(a.z); v[3]=f2bf(a.w);
        v[4]=f2bf(b.x); v[5]=f2bf(b.y); v[6]=f2bf(b.z); v[7]=f2bf(b.w);
        *(bf16x8*)&As[row * 128 + ((j ^ (row & 15)) << 3)] = v;
    }
    const ushort_t* Wz = Wt_all + (size_t)z * 16384;
    #pragma unroll
    for (int i = 0; i < 8; ++i) {
        const int seg = w * 8 + i;
        const int row = seg * 4 + (l >> 4);
        const int j = (l & 15) ^ (row & 15);
        GLOAD16(Wz + row * 128 + j * 8, &Bs[seg * 512]);
    }
    __syncthreads();

    bf16x8 af[4];
    #pragma unroll
    for (int kc = 0; kc < 4; ++kc)
        af[kc] = *(const bf16x8*)&As[(w * 16 + ln) * 128 + (((kc * 4 + lg) ^ ln) << 3)];

    f32x4 acc[8];
    #pragma unroll
    for (int nt = 0; nt < 8; ++nt) acc[nt] = (f32x4){0.f,0.f,0.f,0.f};
    #pragma unroll
    for (int nt = 0; nt < 8; ++nt)
        #pragma unroll
        for (int kc = 0; kc < 4; ++kc) {
            const bf16x8 bn = *(const bf16x8*)&Bs[(nt * 16 + ln) * 128 + (((kc * 4 + lg) ^ ln) << 3)];
            acc[nt] = __builtin_amdgcn_mfma_f32_16x16x32_bf16(af[kc], bn, acc[nt], 0, 0, 0);
        }

    const float* bias = (z < 8 ? bq : z < 16 ? bk : bv) + (z & 7) * 128;
    ushort_t* outp = (z < 8 ? Qb : z < 16 ? Kb : Vb);
    const float scale = z < 8 ? 0.08838834764831845f : 1.0f;
    const int h = z & 7;
    #pragma unroll
    for (int nt = 0; nt < 8; ++nt) {
        const float bb = bias[nt * 16 + ln];
        #pragma unroll
        for (int j2 = 0; j2 < 4; ++j2) {
            const int r = m0 + w * 16 + lg * 4 + j2;
            const int b = r >> 11, s = r & 2047;
            outp[((size_t)((b << 3) + h) * 2048 + s) * 128 + nt * 16 + ln] =
                f2bf((acc[nt][j2] + bb) * scale);
        }
    }
}

// ============ Kernel 2: flash attention, kv-split x2 ============
// grid 512 (XCD-chunked): (split s, bh, q-tile of 128). block 256 = 4 waves,
// wave owns 32 q-rows. launch_bounds(256,2) -> 2 blocks/CU (8 waves/CU).
// Swapped QK^T (S^T = K.Q^T): lane owns 1 q-col, 32 kv in regs. In-lane softmax
// + defer-max (T13). P -> PV B-frag via cvt_pk + permlane32_swap (T12).
// PV: O^T = V^T.P^T. Partial O (unnormalized bf16) + (m,l) to global; merged later.
__global__ __launch_bounds__(256, 2) void attn_kernel(
    const ushort_t* __restrict__ Q, const ushort_t* __restrict__ K,
    const ushort_t* __restrict__ V, ushort_t* __restrict__ Opart,
    float2* __restrict__ ml)
{
    __shared__ ushort_t sh[32768];         // 64KB: Ks dbuf 2x8192, Vt 16384 (elems)
    ushort_t* Vt = sh + 16384;             // 128 rows x 128 elems (256B rows, 16 slots)

    const int tid = threadIdx.x;
    const int w = tid >> 6, l = tid & 63;
    const int ln5 = l & 31, h5 = l >> 5;

    const int id  = blockIdx.x;
    const int id2 = (id & 7) * 64 + (id >> 3);   // bijective over 512
    const int s   = id2 >> 8;                    // kv split 0/1
    const int bh  = (id2 >> 4) & 15;
    const int q0  = (id2 & 15) << 7;             // 128 q-rows per block
    const int kv0 = s << 10;                     // 1024 kv per split

    const size_t base = (size_t)bh * Sq * Hq;
    const ushort_t* Qp = Q + base;
    const ushort_t* Kp = K + base + (size_t)kv0 * Hq;
    const ushort_t* Vp = V + base + (size_t)kv0 * Hq;

    // Q as B-frags: col n = q = ln5, k = kc*16 + h5*8 + j
    bf16x8 qf[8];
    {
        const ushort_t* qrow = Qp + (size_t)(q0 + w * 32 + ln5) * Hq;
        #pragma unroll
        for (int kc = 0; kc < 8; ++kc)
            qf[kc] = *(const bf16x8*)(qrow + kc * 16 + h5 * 8);
    }

    const int kv2 = (tid & 31) * 2;
    const int d8  = (tid >> 5) * 8;

    f32x16 po[4];
    #pragma unroll
    for (int dt = 0; dt < 4; ++dt)
        #pragma unroll
        for (int r = 0; r < 16; ++r) po[dt][r] = 0.f;
    float m_ = -1e30f, l_ = 0.f;

    // ---- prologue: stage tile 0 ----
    #pragma unroll
    for (int i = 0; i < 4; ++i) {
        const int seg = w * 4 + i;
        const int row = seg * 4 + (l >> 4);
        const int j = (l & 15) ^ (row & 15);
        GLOAD16(Kp + (size_t)row * Hq + j * 8, &sh[seg * 512]);
    }
    bf16x8 va0 = *(const bf16x8*)(Vp + (size_t)kv2 * Hq + d8);
    bf16x8 va1 = *(const bf16x8*)(Vp + (size_t)(kv2 + 1) * Hq + d8);
    bf16x8 vb0 = *(const bf16x8*)(Vp + (size_t)kv2 * Hq + d8 + 64);
    bf16x8 vb1 = *(const bf16x8*)(Vp + (size_t)(kv2 + 1) * Hq + d8 + 64);
    __syncthreads();
    #pragma unroll
    for (int jj = 0; jj < 8; ++jj) {
        const int r1 = d8 + jj, r2 = d8 + 64 + jj;
        *(uint_t*)&Vt[r1 * 128 + ((((kv2 >> 3) ^ (r1 & 15))) << 3) + (kv2 & 7)] =
            (uint_t)(ushort_t)va0[jj] | ((uint_t)(ushort_t)va1[jj] << 16);
        *(uint_t*)&Vt[r2 * 128 + ((((kv2 >> 3) ^ (r2 & 15))) << 3) + (kv2 & 7)] =
            (uint_t)(ushort_t)vb0[jj] | ((uint_t)(ushort_t)vb1[jj] << 16);
    }
    __syncthreads();

    const int NT = 1024 / 64;                 // 16 tiles per split
    for (int t = 0; t < NT; ++t) {
        const int buf = t & 1;
        const ushort_t* Ksb = sh + buf * 8192;

        // ---- QK^T (S^T = K . Q^T) ----
        f32x16 st[2];
        #pragma unroll
        for (int mt = 0; mt < 2; ++mt)
            #pragma unroll
            for (int r = 0; r < 16; ++r) st[mt][r] = 0.f;

        __builtin_amdgcn_s_setprio(1);
        #pragma unroll
        for (int kc = 0; kc < 8; ++kc) {
            #pragma unroll
            for (int mt = 0; mt < 2; ++mt) {
                const int row = mt * 32 + ln5;
                const int slot = (kc * 2 + h5) ^ (row & 15);
                const bf16x8 ka = *(const bf16x8*)&Ksb[row * 128 + (slot << 3)];
                st[mt] = __builtin_amdgcn_mfma_f32_32x32x16_bf16(ka, qf[kc], st[mt], 0, 0, 0);
            }
        }
        __builtin_amdgcn_s_setprio(0);

        // ---- prefetch tile t+1 ----
        if (t + 1 < NT) {
            const int k0n = (t + 1) * 64;
            #pragma unroll
            for (int i = 0; i < 4; ++i) {
                const int seg = w * 4 + i;
                const int row = seg * 4 + (l >> 4);
                const int j = (l & 15) ^ (row & 15);
                GLOAD16(Kp + (size_t)(k0n + row) * Hq + j * 8, &sh[(buf ^ 1) * 8192 + seg * 512]);
            }
            va0 = *(const bf16x8*)(Vp + (size_t)(k0n + kv2) * Hq + d8);
            va1 = *(const bf16x8*)(Vp + (size_t)(k0n + kv2 + 1) * Hq + d8);
            vb0 = *(const bf16x8*)(Vp + (size_t)(k0n + kv2) * Hq + d8 + 64);
            vb1 = *(const bf16x8*)(Vp + (size_t)(k0n + kv2 + 1) * Hq + d8 + 64);
        }

        // ---- in-lane online softmax with defer-max (T13) ----
        float mxv[16];
        #pragma unroll
        for (int r = 0; r < 16; ++r) mxv[r] = fmaxf(st[0][r], st[1][r]);
        #pragma unroll
        for (int sd = 8; sd >= 1; sd >>= 1)
            #pragma unroll
            for (int i = 0; i < sd; ++i) mxv[i] = fmaxf(mxv[i], mxv[i + sd]);
        float mx = mxv[0];
        mx = fmaxf(mx, __shfl_xor(mx, 32));

        const bool anyup = __any(mx > m_ + 8.0f);
        float sc = 1.0f;
        if (anyup) {
            const float mn = fmaxf(m_, mx);
            sc = __expf(m_ - mn);             // first tile: exp(-1e30) = 0
            m_ = mn;
        }

        float pe[32];
        #pragma unroll
        for (int mt = 0; mt < 2; ++mt)
            #pragma unroll
            for (int r = 0; r < 16; ++r)
                pe[mt * 16 + r] = __expf(st[mt][r] - m_);

        float sv[16];
        #pragma unroll
        for (int r = 0; r < 16; ++r) sv[r] = pe[r] + pe[16 + r];
        #pragma unroll
        for (int sd = 8; sd >= 1; sd >>= 1)
            #pragma unroll
            for (int i = 0; i < sd; ++i) sv[i] += sv[i + sd];
        float rs = sv[0];
        rs += __shfl_xor(rs, 32);
        l_ = l_ * sc + rs;

        // ---- P -> PV B-frags via cvt_pk + permlane32_swap (T12) ----
        bf16x8 pb[4];
        #pragma unroll
        for (int ks = 0; ks < 4; ++ks) {
            const int o = (ks >> 1) * 16 + (ks & 1) * 8;
            uint_t wA = cvtpk_bf16(pe[o + 0], pe[o + 1]);
            uint_t wB = cvtpk_bf16(pe[o + 4], pe[o + 5]);
            pswap32(wA, wB);
            uint_t wC = cvtpk_bf16(pe[o + 2], pe[o + 3]);
            uint_t wD = cvtpk_bf16(pe[o + 6], pe[o + 7]);
            pswap32(wC, wD);
            uint4v wv; wv[0] = wA; wv[1] = wC; wv[2] = wB; wv[3] = wD;
            pb[ks] = __builtin_bit_cast(bf16x8, wv);
        }

        if (anyup) {
            #pragma unroll
            for (int dt = 0; dt < 4; ++dt)
                #pragma unroll
                for (int r = 0; r < 16; ++r) po[dt][r] *= sc;
        }

        // ---- PV: O^T = V^T . P^T ----
        __builtin_amdgcn_s_setprio(1);
        #pragma unroll
        for (int dt = 0; dt < 4; ++dt) {
            #pragma unroll
            for (int ks = 0; ks < 4; ++ks) {
                const int row = dt * 32 + ln5;
                const int slot = (ks * 2 + h5) ^ (row & 15);
                const bf16x8 va = *(const bf16x8*)&Vt[row * 128 + (slot << 3)];
                po[dt] = __builtin_amdgcn_mfma_f32_32x32x16_bf16(va, pb[ks], po[dt], 0, 0, 0);
            }
        }
        __builtin_amdgcn_s_setprio(0);

        __syncthreads();   // PV reads done; prefetched K landed; V regs ready
        if (t + 1 < NT) {
            #pragma unroll
            for (int jj = 0; jj < 8; ++jj) {
                const int r1 = d8 + jj, r2 = d8 + 64 + jj;
                *(uint_t*)&Vt[r1 * 128 + ((((kv2 >> 3) ^ (r1 & 15))) << 3) + (kv2 & 7)] =
                    (uint_t)(ushort_t)va0[jj] | ((uint_t)(ushort_t)va1[jj] << 16);
                *(uint_t*)&Vt[r2 * 128 + ((((kv2 >> 3) ^ (r2 & 15))) << 3) + (kv2 & 7)] =
                    (uint_t)(ushort_t)vb0[jj] | ((uint_t)(ushort_t)vb1[jj] << 16);
            }
        }
        __syncthreads();
    }

    // ---- epilogue: unnormalized O^T -> LDS bounce (264B rows) -> Opart + ml ----
    // wave-private region: byte base w*8448, row q (0..31) stride 264B, col d*2B.
    char* shb = (char*)sh;
    char* wb = shb + w * 8448;
    #pragma unroll
    for (int dt = 0; dt < 4; ++dt)
        #pragma unroll
        for (int r = 0; r < 16; r += 2) {
            const int d = dt * 32 + (r & 3) + 8 * (r >> 2) + 4 * h5;
            const uint_t pk = cvtpk_bf16(po[dt][r], po[dt][r + 1]);
            *(uint_t*)(wb + ln5 * 264 + d * 2) = pk;
        }
    const int rid0 = (s * 16 + bh) * 2048 + q0 + w * 32;
    #pragma unroll
    for (int rb = 0; rb < 8; ++rb) {
        const int qr = rb * 4 + (l >> 4);
        const char* rp = wb + qr * 264 + (l & 15) * 16;
        u64x2 vv;
        vv[0] = *(const u64*)rp;
        vv[1] = *(const u64*)(rp + 8);
        *(u64x2*)(Opart + (size_t)(rid0 + qr) * 128 + (l & 15) * 8) = vv;
    }
    if (h5 == 0)
        ml[rid0 + ln5] = make_float2(m_, l_);
}

// ============ Kernel 2b: merge the two kv-split partials ============
// grid 2048, block 256: thread = (row rid, 8 d-elems). out = ob [b*S+q][h*128+d] bf16.
__global__ __launch_bounds__(256) void merge_kernel(
    const ushort_t* __restrict__ Opart, const float2* __restrict__ ml,
    ushort_t* __restrict__ ob)
{
    const int t = threadIdx.x;
    const int rid = blockIdx.x * 16 + (t >> 4);
    const int d0 = (t & 15) * 8;
    const float2 ml1 = ml[rid];
    const float2 ml2 = ml[32768 + rid];
    const float M = fmaxf(ml1.x, ml2.x);
    const float w1 = __expf(ml1.x - M), w2 = __expf(ml2.x - M);
    const float inv = 1.0f / (w1 * ml1.y + w2 * ml2.y);
    const bf16x8 o1 = *(const bf16x8*)&Opart[(size_t)rid * 128 + d0];
    const bf16x8 o2 = *(const bf16x8*)&Opart[(size_t)(32768 + rid) * 128 + d0];
    const int bh = rid >> 11, q = rid & 2047;
    const int b = bh >> 3, h = bh & 7;
    ushort_t* dst = ob + (size_t)(b * 2048 + q) * 1024 + h * 128 + d0;
    ushort4_t lo, hi;
    #pragma unroll
    for (int j = 0; j < 8; ++j) {
        const float v = (w1 * bf2f((ushort_t)o1[j]) + w2 * bf2f((ushort_t)o2[j])) * inv;
        if (j < 4) lo[j] = f2bf(v); else hi[j - 4] = f2bf(v);
    }
    *(ushort4_t*)dst = lo;
    *(ushort4_t*)(dst + 4) = hi;
}

// ============ Kernel 3: MFMA GEMM, BM=32: C[M,N] = A[M,K]@Bt[N,K]^T + bias ============
// grid (M/32, N/128), block 256; wave w: rows (w&1)*16..+15, cols (w>>1)*64..+63.
__global__ __launch_bounds__(256) void gemm32_kernel(
    const ushort_t* __restrict__ A, const ushort_t* __restrict__ Bt,
    const float* __restrict__ bias, float* __restrict__ Cf, ushort_t* __restrict__ Cb,
    int N, int K, int KS, int relu)
{
    __shared__ ushort_t As[32 * 128];
    __shared__ ushort_t Bs[128 * 128];
    const int tid = threadIdx.x;
    const int w = tid >> 6, l = tid & 63, lg = l >> 4, ln = l & 15;
    const int m0 = blockIdx.x << 5;
    const int n0 = blockIdx.y << 7;
    const int rw = (w & 1) * 16;
    const int cw = (w >> 1) * 4;     // col-tile base (x16)

    f32x4 acc[4];
    #pragma unroll
    for (int nt = 0; nt < 4; ++nt) acc[nt] = (f32x4){0.f,0.f,0.f,0.f};

    for (int ks = 0; ks < KS; ++ks) {
        const int k0 = ks << 7;
        #pragma unroll
        for (int i = 0; i < 2; ++i) {
            const int seg = w * 2 + i;
            const int row = seg * 4 + (l >> 4);
            const int j = (l & 15) ^ (row & 15);
            GLOAD16(A + (size_t)(m0 + row) * K + k0 + j * 8, &As[seg * 512]);
        }
        #pragma unroll
        for (int i = 0; i < 8; ++i) {
            const int seg = w * 8 + i;
            const int row = seg * 4 + (l >> 4);
            const int j = (l & 15) ^ (row & 15);
            GLOAD16(Bt + (size_t)(n0 + row) * K + k0 + j * 8, &Bs[seg * 512]);
        }
        __syncthreads();

        bf16x8 af[4];
        #pragma unroll
        for (int kc = 0; kc < 4; ++kc)
            af[kc] = *(const bf16x8*)&As[(rw + ln) * 128 + (((kc * 4 + lg) ^ ln) << 3)];
        #pragma unroll
        for (int nt = 0; nt < 4; ++nt)
            #pragma unroll
            for (int kc = 0; kc < 4; ++kc) {
                const bf16x8 bn = *(const bf16x8*)&Bs[((cw + nt) * 16 + ln) * 128 + (((kc * 4 + lg) ^ ln) << 3)];
                acc[nt] = __builtin_amdgcn_mfma_f32_16x16x32_bf16(af[kc], bn, acc[nt], 0, 0, 0);
            }
        __syncthreads();
    }

    #pragma unroll
    for (int nt = 0; nt < 4; ++nt) {
        const int col = n0 + (cw + nt) * 16 + ln;
        const float bb = bias[col];
        #pragma unroll
        for (int j2 = 0; j2 < 4; ++j2) {
            const int r = m0 + rw + lg * 4 + j2;
            float v = acc[nt][j2] + bb;
            if (relu) v = fmaxf(v, 0.f);
            if (Cb) Cb[(size_t)r * N + col] = f2bf(v);
            else    Cf[(size_t)r * N + col] = v;
        }
    }
}

// ============ LayerNorm (optional residual, optional bf16 copy) ============
__global__ __launch_bounds__(256) void ln_kernel(
    const float* __restrict__ in, const float* __restrict__ res,
    const float* __restrict__ g, const float* __restrict__ bta,
    float* __restrict__ out, ushort_t* __restrict__ out_bf)
{
    const int lane = threadIdx.x & 63;
    const int row  = (blockIdx.x << 2) + (threadIdx.x >> 6);
    const int base = row * 128 + lane * 2;
    float2 v = *(const float2*)&in[base];
    if (res) {
        const float2 rv = *(const float2*)&res[base];
        v.x += rv.x; v.y += rv.y;
    }
    float s  = v.x + v.y;
    float sq = v.x * v.x + v.y * v.y;
    #pragma unroll
    for (int mm = 1; mm <= 32; mm <<= 1) {
        s  += __shfl_xor(s, mm);
        sq += __shfl_xor(sq, mm);
    }
    const float mean = s * (1.0f / 128.0f);
    const float var  = sq * (1.0f / 128.0f) - mean * mean;
    const float rstd = rsqrtf(var + 1e-5f);
    const float2 gv = *(const float2*)&g[lane * 2];
    const float2 bv = *(const float2*)&bta[lane * 2];
    float2 o;
    o.x = (v.x - mean) * rstd * gv.x + bv.x;
    o.y = (v.y - mean) * rstd * gv.y + bv.y;
    *(float2*)&out[base] = o;
    if (out_bf) {
        const uint_t pk = (uint_t)f2bf(o.x) | ((uint_t)f2bf(o.y) << 16);
        *(uint_t*)&out_bf[base] = pk;
    }
}

extern "C" void kernel_launch(void* const* d_in, const int* in_sizes, int n_in,
                              void* d_out, int out_size, void* d_ws, size_t ws_size,
                              hipStream_t stream)
{
    const float* x   = (const float*)d_in[0];
    const float* Wq  = (const float*)d_in[1];
    const float* bq  = (const float*)d_in[2];
    const float* Wk  = (const float*)d_in[3];
    const float* bk  = (const float*)d_in[4];
    const float* Wv  = (const float*)d_in[5];
    const float* bv  = (const float*)d_in[6];
    const float* Wo  = (const float*)d_in[7];
    const float* bo  = (const float*)d_in[8];
    const float* W1  = (const float*)d_in[9];
    const float* b1  = (const float*)d_in[10];
    const float* W2  = (const float*)d_in[11];
    const float* b2  = (const float*)d_in[12];
    const float* g1  = (const float*)d_in[13];
    const float* be1 = (const float*)d_in[14];
    const float* g2  = (const float*)d_in[15];
    const float* be2 = (const float*)d_in[16];
    (void)in_sizes; (void)n_in; (void)out_size; (void)ws_size;

    ushort_t* Wt_all = (ushort_t*)d_ws;              // 393216
    ushort_t* Wot = Wt_all + 393216;                 // 131072
    ushort_t* W1t = Wot + 131072;                    // 32768
    ushort_t* W2t = W1t + 32768;                     // 32768
    ushort_t* Qb  = W2t + 32768;                     // 3 x 4194304
    ushort_t* Kb  = Qb + 4194304;
    ushort_t* Vb  = Kb + 4194304;
    ushort_t* ob  = Vb + 4194304;                    // 4194304
    ushort_t* yb  = ob + 4194304;                    // 524288
    ushort_t* h1  = yb + 524288;                     // 1048576
    // region R: Opart (8388608 us) + ml (65536 float2); y0/y/f alias Opart (dead after merge)
    ushort_t* Opart = h1 + 1048576;
    float2*   ml    = (float2*)(Opart + 8388608);
    float* y0 = (float*)Opart;                       // 524288 f32 each
    float* y  = y0 + 524288;
    float* f  = y  + 524288;

    tw_kernel   <<<dim3(128, 27), 256, 0, stream>>>(Wq, Wk, Wv, Wo, W1, W2, Wt_all, Wot, W1t, W2t);
    qkv_gemm    <<<dim3(64, 24),  256, 0, stream>>>(x, Wt_all, bq, bk, bv, Qb, Kb, Vb);
    attn_kernel <<<dim3(512),     256, 0, stream>>>(Qb, Kb, Vb, Opart, ml);
    merge_kernel<<<dim3(2048),    256, 0, stream>>>(Opart, ml, ob);
    gemm32_kernel<<<dim3(128, 1), 256, 0, stream>>>(ob, Wot, bo, y0, nullptr, 128, 1024, 8, 0);
    ln_kernel   <<<1024,          256, 0, stream>>>(y0, nullptr, g1, be1, y, yb);
    gemm32_kernel<<<dim3(128, 2), 256, 0, stream>>>(yb, W1t, b1, nullptr, h1, 256, 128, 1, 1);
    gemm32_kernel<<<dim3(128, 1), 256, 0, stream>>>(h1, W2t, b2, f, nullptr, 128, 256, 2, 1);
    ln_kernel   <<<1024,          256, 0, stream>>>(y, f, g2, be2, (float*)d_out, nullptr);
}